// Round 2
// baseline (374.198 us; speedup 1.0000x reference)
//
#include <hip/hip_runtime.h>
#include <hip/hip_bf16.h>

#define BB 16
#define NN 4096
#define SS 1024
#define C1 128
#define C2 256
#define CIN 384
#define CO 128

typedef __bf16 bf16x8 __attribute__((ext_vector_type(8)));
typedef float f32x4 __attribute__((ext_vector_type(4)));

// ------- Kernel 1: 3-NN + weights, top-4 scan, tie flag --------------------
// FROZEN: byte-identical to r12 (passing). Clang's default contraction here
// compiles to the reference-matching arithmetic; ANY restructuring (r13's
// split/dual-chain) changes the fusion pattern and breaks tie sites.
__global__ __launch_bounds__(256) void knn_kernel(
    const float* __restrict__ xyz1, const float* __restrict__ xyz2,
    int* __restrict__ idx4, float* __restrict__ w4)
{
    __shared__ float4 pts[SS];   // x, y, z, |p|^2  -> 16 KB
    const int b = blockIdx.y;
    const float* p2 = xyz2 + (size_t)b * SS * 3;
    for (int i = threadIdx.x; i < SS; i += 256) {
        float x = p2[i * 3 + 0], y = p2[i * 3 + 1], z = p2[i * 3 + 2];
        pts[i] = make_float4(x, y, z, x * x + y * y + z * z);
    }
    __syncthreads();

    const int n = blockIdx.x * 256 + threadIdx.x;
    const float* p1 = xyz1 + ((size_t)b * NN + n) * 3;
    const float x = p1[0], y = p1[1], z = p1[2];
    const float s1 = x * x + y * y + z * z;

    float d0 = 3.4e38f, d1 = 3.4e38f, d2 = 3.4e38f, d3 = 3.4e38f;
    int i0 = 0, i1 = 0, i2 = 0, i3 = 0;
    #pragma unroll 4
    for (int s = 0; s < SS; ++s) {
        float4 p = pts[s];
        float d = s1 + p.w - 2.0f * (x * p.x + y * p.y + z * p.z);
        bool lt0 = d < d0, lt1 = d < d1, lt2 = d < d2, lt3 = d < d3;
        float nd3 = lt2 ? d2 : (lt3 ? d : d3); int ni3 = lt2 ? i2 : (lt3 ? s : i3);
        float nd2 = lt1 ? d1 : (lt2 ? d : d2); int ni2 = lt1 ? i1 : (lt2 ? s : i2);
        float nd1 = lt0 ? d0 : (lt1 ? d : d1); int ni1 = lt0 ? i0 : (lt1 ? s : i1);
        d0 = lt0 ? d : d0;                     i0 = lt0 ? s : i0;
        d1 = nd1; i1 = ni1; d2 = nd2; i2 = ni2; d3 = nd3; i3 = ni3;
    }
    float r0 = 1.0f / (d0 + 1e-8f);
    float r1 = 1.0f / (d1 + 1e-8f);
    float r2 = 1.0f / (d2 + 1e-8f);
    float rs = r0 + r1 + r2;
    bool tie = (d2 == d3);
    size_t base = ((size_t)b * NN + n) * 4;
    idx4[base + 0] = i0; idx4[base + 1] = i1;
    idx4[base + 2] = i2; idx4[base + 3] = i3;
    w4[base + 0] = r0 / rs; w4[base + 1] = r1 / rs;
    w4[base + 2] = r2 / rs; w4[base + 3] = tie ? -1.0f : 0.0f;
}

// ---------------- Kernel 2: transpose points2 f32[C2,S] -> f32[S,C2] -------
__global__ __launch_bounds__(256) void p2t_kernel(
    const float* __restrict__ p2, float* __restrict__ p2t)
{
    __shared__ float tile[64][65];
    const int b = blockIdx.z;
    const int s0 = blockIdx.x * 64, c0 = blockIdx.y * 64;
    for (int i = threadIdx.x; i < 64 * 64; i += 256) {
        int s = i & 63, c = i >> 6;
        tile[c][s] = p2[((size_t)b * C2 + c0 + c) * SS + s0 + s];
    }
    __syncthreads();
    for (int i = threadIdx.x; i < 64 * 64; i += 256) {
        int c = i & 63, s = i >> 6;
        p2t[((size_t)b * SS + s0 + s) * C2 + c0 + c] = tile[c][s];
    }
}

// ------- Kernel 2c: split conv weights f32 -> bf16 hi/lo planes (once) -----
__global__ __launch_bounds__(256) void wprep_kernel(
    const float* __restrict__ fw, const float* __restrict__ w1,
    const float* __restrict__ w2,
    __bf16* __restrict__ Whf, __bf16* __restrict__ Wlf,
    __bf16* __restrict__ Wh1, __bf16* __restrict__ Wl1,
    __bf16* __restrict__ Wh2, __bf16* __restrict__ Wl2)
{
    int t = blockIdx.x * 256 + threadIdx.x;
    float v; __bf16 *oh, *ol; int idx;
    if (t < 49152)      { idx = t;         v = fw[idx]; oh = Whf; ol = Wlf; }
    else if (t < 65536) { idx = t - 49152; v = w1[idx]; oh = Wh1; ol = Wl1; }
    else                { idx = t - 65536; v = w2[idx]; oh = Wh2; ol = Wl2; }
    __bf16 h = (__bf16)v;
    oh[idx] = h; ol[idx] = (__bf16)(v - (float)h);
}

// ------- Kernel 2b: tie resolver (unchanged logic from r12) ----------------
__global__ __launch_bounds__(256) void tie_eval_kernel(
    const float* __restrict__ p2t, const float* __restrict__ points1,
    const int* __restrict__ idx4, float* __restrict__ w4,
    const float* __restrict__ fw, const float* __restrict__ fb,
    const float* __restrict__ fg, const float* __restrict__ fbt,
    const float* __restrict__ fm, const float* __restrict__ fv,
    const float* __restrict__ w1m, const float* __restrict__ b1,
    const float* __restrict__ g1, const float* __restrict__ bt1,
    const float* __restrict__ m1, const float* __restrict__ v1,
    const float* __restrict__ w2m, const float* __restrict__ b2,
    const float* __restrict__ g2, const float* __restrict__ bt2,
    const float* __restrict__ m2, const float* __restrict__ v2)
{
    __shared__ float Xs[4][2][CIN];
    __shared__ float XT[4][2][CO];
    __shared__ float Hs[4][2][CO];
    const int wave = threadIdx.x >> 6, lane = threadIdx.x & 63;
    const int n = blockIdx.x * 4 + wave;
    const int b = blockIdx.y;
    const size_t base = ((size_t)b * NN + n) * 4;
    if (w4[base + 3] != -1.0f) return;

    const int i0 = idx4[base + 0], i1 = idx4[base + 1];
    const int i2 = idx4[base + 2], i3 = idx4[base + 3];
    const float w0 = w4[base + 0], w1 = w4[base + 1], w2 = w4[base + 2];
    const float* P = p2t + (size_t)b * SS * C2;

    for (int c = lane; c < C1; c += 64) {
        float v = points1[((size_t)b * C1 + c) * NN + n];
        Xs[wave][0][c] = v; Xs[wave][1][c] = v;
    }
    for (int c = lane; c < C2; c += 64) {
        float f0 = P[(size_t)i0 * C2 + c], f1 = P[(size_t)i1 * C2 + c];
        float f2 = P[(size_t)i2 * C2 + c], f3 = P[(size_t)i3 * C2 + c];
        float bs = w0 * f0 + w1 * f1;
        Xs[wave][0][C1 + c] = bs + w2 * f2;
        Xs[wave][1][C1 + c] = bs + w2 * f3;
    }
    #pragma unroll
    for (int k = 0; k < 2; ++k) {
        int oc = lane + 64 * k;
        float alo = fb[oc], ahi = fb[oc];
        for (int c = 0; c < CIN; ++c) {
            float wv = fw[(size_t)oc * CIN + c];
            alo += wv * Xs[wave][0][c];
            ahi += wv * Xs[wave][1][c];
        }
        float s = fg[oc] * (1.0f / sqrtf(fv[oc] + 1e-5f));
        XT[wave][0][oc] = fmaxf(s * (alo - fm[oc]) + fbt[oc], 0.0f);
        XT[wave][1][oc] = fmaxf(s * (ahi - fm[oc]) + fbt[oc], 0.0f);
    }
    #pragma unroll
    for (int k = 0; k < 2; ++k) {
        int oc = lane + 64 * k;
        float alo = b1[oc], ahi = b1[oc];
        for (int c = 0; c < CO; ++c) {
            float wv = w1m[(size_t)oc * CO + c];
            alo += wv * XT[wave][0][c];
            ahi += wv * XT[wave][1][c];
        }
        float s = g1[oc] * (1.0f / sqrtf(v1[oc] + 1e-5f));
        Hs[wave][0][oc] = fmaxf(s * (alo - m1[oc]) + bt1[oc], 0.0f);
        Hs[wave][1][oc] = fmaxf(s * (ahi - m1[oc]) + bt1[oc], 0.0f);
    }
    float e = 0.0f;
    #pragma unroll
    for (int k = 0; k < 2; ++k) {
        int oc = lane + 64 * k;
        float alo = b2[oc], ahi = b2[oc];
        for (int c = 0; c < CO; ++c) {
            float wv = w2m[(size_t)oc * CO + c];
            alo += wv * Hs[wave][0][c];
            ahi += wv * Hs[wave][1][c];
        }
        float s = g2[oc] * (1.0f / sqrtf(v2[oc] + 1e-5f));
        float olo = fmaxf(s * (alo - m2[oc]) + bt2[oc] + XT[wave][0][oc], 0.0f);
        float ohi = fmaxf(s * (ahi - m2[oc]) + bt2[oc] + XT[wave][1][oc], 0.0f);
        e = fmaxf(e, fabsf(olo - ohi));
    }
    for (int off = 32; off; off >>= 1) e = fmaxf(e, __shfl_xor(e, off));
    if (lane == 0) {
        if (e > 0.085f) { w4[base + 3] = 0.0f; }
        else { w4[base + 2] = 0.5f * w2; w4[base + 3] = 0.5f * w2; }
    }
}

// ---------------- Kernel 3: build X (bf16 hi/lo planes) --------------------
__global__ __launch_bounds__(256) void buildx_kernel(
    const float* __restrict__ points1,
    const float* __restrict__ p2t,
    const int* __restrict__ idx4, const float* __restrict__ w4,
    __bf16* __restrict__ Xh, __bf16* __restrict__ Xl)
{
    __shared__ float t1[128][66];
    const int b = blockIdx.y;
    const int n0 = blockIdx.x * 64;
    for (int i = threadIdx.x; i < 128 * 64; i += 256) {
        int j = i & 63, c = i >> 6;
        t1[c][j] = points1[((size_t)b * C1 + c) * NN + n0 + j];
    }
    __syncthreads();
    for (int i = threadIdx.x; i < 128 * 64; i += 256) {
        int c = i & 127, j = i >> 7;
        float v = t1[c][j];
        __bf16 h = (__bf16)v;
        size_t o = ((size_t)b * NN + n0 + j) * CIN + c;
        Xh[o] = h; Xl[o] = (__bf16)(v - (float)h);
    }
    for (int i = threadIdx.x; i < 64 * C2; i += 256) {
        int c = i & 255, j = i >> 8;
        int n = n0 + j;
        size_t ib = ((size_t)b * NN + n) * 4;
        int s0 = idx4[ib + 0], s1 = idx4[ib + 1];
        int s2 = idx4[ib + 2], s3 = idx4[ib + 3];
        float w0 = w4[ib + 0], w1 = w4[ib + 1];
        float w2 = w4[ib + 2], w3 = w4[ib + 3];
        const float* base = p2t + (size_t)b * SS * C2;
        float v = w0 * base[(size_t)s0 * C2 + c]
                + w1 * base[(size_t)s1 * C2 + c]
                + w2 * base[(size_t)s2 * C2 + c]
                + w3 * base[(size_t)s3 * C2 + c];
        __bf16 h = (__bf16)v;
        size_t o = ((size_t)b * NN + n) * CIN + C1 + c;
        Xh[o] = h; Xl[o] = (__bf16)(v - (float)h);
    }
}

// ------- Kernels 4-6: split-bf16 MFMA GEMM v2 ------------------------------
// A and W pre-split into bf16 hi/lo planes (zero load-time conversion).
// 128-row blocks, 32 rows/wave. acc += hi*wh + lo*wh + hi*wl.
// MODE 0: out = relu(bn(..)) -> bf16 hi/lo planes [M,128]
// MODE 1: out = relu(bn(..) + skip) -> f32 transposed [B,128,N] via LDS tile
template<int K, int MODE>
__global__ __launch_bounds__(256) void gemm_bn_kernel(
    const __bf16* __restrict__ Ah, const __bf16* __restrict__ Al,
    const __bf16* __restrict__ Wh, const __bf16* __restrict__ Wl,
    const float* __restrict__ cb,  const float* __restrict__ gg,
    const float* __restrict__ bbta, const float* __restrict__ mm,
    const float* __restrict__ vv,
    const __bf16* __restrict__ skiph, const __bf16* __restrict__ skipl,
    __bf16* __restrict__ outh, __bf16* __restrict__ outl,
    float* __restrict__ outf)
{
    __shared__ __attribute__((aligned(16))) __bf16 wls_h[128 * 40]; // 10 KB
    __shared__ __attribute__((aligned(16))) __bf16 wls_l[128 * 40]; // 10 KB
    __shared__ float s_s[128], s_t[128];
    __shared__ float tile[32][132];   // MODE1 transpose staging
    const int tid = threadIdx.x;
    if (tid < 128) {
        float s = gg[tid] * (1.0f / sqrtf(vv[tid] + 1e-5f));
        float t = (cb[tid] - mm[tid]) * s + bbta[tid];
        s_s[tid] = s; s_t[tid] = t;
    }
    const int wave = tid >> 6, lane = tid & 63;
    const int m = lane & 15, q = lane >> 4;
    const size_t r0 = (size_t)blockIdx.x * 128 + wave * 32;

    f32x4 acc[2][8] = {};
    const __bf16* pAh = Ah + (r0 + m) * (size_t)K + q * 8;
    const __bf16* pAl = Al + (r0 + m) * (size_t)K + q * 8;

    const int wrow = tid >> 1, whf = tid & 1;
    for (int kk = 0; kk < K; kk += 32) {
        __syncthreads();
        {   // stage Wh/Wl tile (each thread: 16 elems per plane)
            size_t g = (size_t)wrow * K + kk + whf * 16;
            int lo = wrow * 40 + whf * 16;
            *(uint4*)&wls_h[lo]     = *(const uint4*)&Wh[g];
            *(uint4*)&wls_h[lo + 8] = *(const uint4*)&Wh[g + 8];
            *(uint4*)&wls_l[lo]     = *(const uint4*)&Wl[g];
            *(uint4*)&wls_l[lo + 8] = *(const uint4*)&Wl[g + 8];
        }
        __syncthreads();
        bf16x8 ah0 = *(const bf16x8*)(pAh + kk);
        bf16x8 al0 = *(const bf16x8*)(pAl + kk);
        bf16x8 ah1 = *(const bf16x8*)(pAh + 16 * (size_t)K + kk);
        bf16x8 al1 = *(const bf16x8*)(pAl + 16 * (size_t)K + kk);
        #pragma unroll
        for (int ot = 0; ot < 8; ++ot) {
            bf16x8 bh = *(const bf16x8*)&wls_h[(ot * 16 + m) * 40 + q * 8];
            bf16x8 bl = *(const bf16x8*)&wls_l[(ot * 16 + m) * 40 + q * 8];
            acc[0][ot] = __builtin_amdgcn_mfma_f32_16x16x32_bf16(ah0, bh, acc[0][ot], 0, 0, 0);
            acc[0][ot] = __builtin_amdgcn_mfma_f32_16x16x32_bf16(al0, bh, acc[0][ot], 0, 0, 0);
            acc[0][ot] = __builtin_amdgcn_mfma_f32_16x16x32_bf16(ah0, bl, acc[0][ot], 0, 0, 0);
            acc[1][ot] = __builtin_amdgcn_mfma_f32_16x16x32_bf16(ah1, bh, acc[1][ot], 0, 0, 0);
            acc[1][ot] = __builtin_amdgcn_mfma_f32_16x16x32_bf16(al1, bh, acc[1][ot], 0, 0, 0);
            acc[1][ot] = __builtin_amdgcn_mfma_f32_16x16x32_bf16(ah1, bl, acc[1][ot], 0, 0, 0);
        }
    }

    if (MODE == 0) {
        #pragma unroll
        for (int rt = 0; rt < 2; ++rt) {
            #pragma unroll
            for (int ot = 0; ot < 8; ++ot) {
                int col = ot * 16 + m;
                float sc = s_s[col], sh = s_t[col];
                #pragma unroll
                for (int r = 0; r < 4; ++r) {
                    size_t row = r0 + rt * 16 + q * 4 + r;
                    float val = fmaxf(acc[rt][ot][r] * sc + sh, 0.0f);
                    __bf16 h = (__bf16)val;
                    outh[row * 128 + col] = h;
                    outl[row * 128 + col] = (__bf16)(val - (float)h);
                }
            }
        }
    } else {
        const int bidx = (int)(((size_t)blockIdx.x * 128) >> 12);
        const int nbase = (int)(((size_t)blockIdx.x * 128) & 4095);
        for (int cc = 0; cc < 4; ++cc) {
            __syncthreads();
            #pragma unroll
            for (int oo = 0; oo < 2; ++oo) {
                int ot = cc * 2 + oo;
                int col = ot * 16 + m;
                float sc = s_s[col], sh = s_t[col];
                #pragma unroll
                for (int rt = 0; rt < 2; ++rt) {
                    #pragma unroll
                    for (int r = 0; r < 4; ++r) {
                        int lrow = wave * 32 + rt * 16 + q * 4 + r;
                        size_t row = (size_t)blockIdx.x * 128 + lrow;
                        float val = acc[rt][ot][r] * sc + sh;
                        val += (float)skiph[row * 128 + col] + (float)skipl[row * 128 + col];
                        val = fmaxf(val, 0.0f);
                        tile[oo * 16 + m][lrow] = val;
                    }
                }
            }
            __syncthreads();
            for (int c2 = tid >> 7; c2 < 32; c2 += 2) {
                int nn_ = tid & 127;
                outf[((size_t)bidx * 128 + cc * 32 + c2) * NN + nbase + nn_] = tile[c2][nn_];
            }
        }
    }
}

extern "C" void kernel_launch(void* const* d_in, const int* in_sizes, int n_in,
                              void* d_out, int out_size, void* d_ws, size_t ws_size,
                              hipStream_t stream) {
    const float* xyz1    = (const float*)d_in[0];
    const float* xyz2    = (const float*)d_in[1];
    const float* points1 = (const float*)d_in[2];
    const float* points2 = (const float*)d_in[3];
    const float* fuse_w  = (const float*)d_in[4];
    const float* fuse_b  = (const float*)d_in[5];
    const float* fuse_g  = (const float*)d_in[6];
    const float* fuse_bt = (const float*)d_in[7];
    const float* fuse_m  = (const float*)d_in[8];
    const float* fuse_v  = (const float*)d_in[9];
    const float* c1_w    = (const float*)d_in[10];
    const float* c1_b    = (const float*)d_in[11];
    const float* bn1_g   = (const float*)d_in[12];
    const float* bn1_b   = (const float*)d_in[13];
    const float* bn1_m   = (const float*)d_in[14];
    const float* bn1_v   = (const float*)d_in[15];
    const float* c2_w    = (const float*)d_in[16];
    const float* c2_b    = (const float*)d_in[17];
    const float* bn2_g   = (const float*)d_in[18];
    const float* bn2_b   = (const float*)d_in[19];
    const float* bn2_m   = (const float*)d_in[20];
    const float* bn2_v   = (const float*)d_in[21];

    char* ws = (char*)d_ws;
    int*    idx4 = (int*)(ws);                      // 1 MB
    float*  w4   = (float*)(ws + 1048576);          // 1 MB
    float*  p2t  = (float*)(ws + 2097152);          // 16.78 MB
    __bf16* Xh   = (__bf16*)(ws + 18874368);        // 48 MB
    __bf16* Xl   = (__bf16*)(ws + 69206016);        // 48 MB
    __bf16* Y0h  = (__bf16*)(ws + 119537664);       // 16 MB
    __bf16* Y0l  = (__bf16*)(ws + 136314880);       // 16 MB
    __bf16* Hh   = (__bf16*)(ws + 153092096);       // 16 MB
    __bf16* Hl   = (__bf16*)(ws + 169869312);       // 16 MB
    __bf16* Whf  = (__bf16*)(ws + 186646528);       // 96 KB
    __bf16* Wlf  = (__bf16*)(ws + 186744832);       // 96 KB
    __bf16* Wh1  = (__bf16*)(ws + 186843136);       // 32 KB
    __bf16* Wl1  = (__bf16*)(ws + 186875904);       // 32 KB
    __bf16* Wh2  = (__bf16*)(ws + 186908672);       // 32 KB
    __bf16* Wl2  = (__bf16*)(ws + 186941440);       // 32 KB

    knn_kernel<<<dim3(NN / 256, BB), 256, 0, stream>>>(xyz1, xyz2, idx4, w4);
    p2t_kernel<<<dim3(SS / 64, C2 / 64, BB), 256, 0, stream>>>(points2, p2t);
    wprep_kernel<<<320, 256, 0, stream>>>(fuse_w, c1_w, c2_w,
                                          Whf, Wlf, Wh1, Wl1, Wh2, Wl2);
    tie_eval_kernel<<<dim3(NN / 4, BB), 256, 0, stream>>>(
        p2t, points1, idx4, w4,
        fuse_w, fuse_b, fuse_g, fuse_bt, fuse_m, fuse_v,
        c1_w, c1_b, bn1_g, bn1_b, bn1_m, bn1_v,
        c2_w, c2_b, bn2_g, bn2_b, bn2_m, bn2_v);
    buildx_kernel<<<dim3(NN / 64, BB), 256, 0, stream>>>(points1, p2t, idx4, w4, Xh, Xl);

    const int gblocks = (BB * NN) / 128;   // 512
    gemm_bn_kernel<CIN, 0><<<gblocks, 256, 0, stream>>>(
        Xh, Xl, Whf, Wlf, fuse_b, fuse_g, fuse_bt, fuse_m, fuse_v,
        nullptr, nullptr, Y0h, Y0l, nullptr);
    gemm_bn_kernel<CO, 0><<<gblocks, 256, 0, stream>>>(
        Y0h, Y0l, Wh1, Wl1, c1_b, bn1_g, bn1_b, bn1_m, bn1_v,
        nullptr, nullptr, Hh, Hl, nullptr);
    gemm_bn_kernel<CO, 1><<<gblocks, 256, 0, stream>>>(
        Hh, Hl, Wh2, Wl2, c2_b, bn2_g, bn2_b, bn2_m, bn2_v,
        Y0h, Y0l, nullptr, nullptr, (float*)d_out);
}

// Round 3
// 354.779 us; speedup vs baseline: 1.0547x; 1.0547x over previous
//
#include <hip/hip_runtime.h>
#include <hip/hip_bf16.h>

#define BB 16
#define NN 4096
#define SS 1024
#define C1 128
#define C2 256
#define CIN 384
#define CO 128

#define KCH 4            // knn S-chunks
#define SCH (SS / KCH)   // 256 points per chunk

typedef __bf16 bf16x8 __attribute__((ext_vector_type(8)));
typedef float f32x4 __attribute__((ext_vector_type(4)));

// ------- Kernel 1a: partial 3-NN scan over one S-chunk ---------------------
// FROZEN ARITHMETIC: the distance expression and the 4-slot insertion chain
// are byte-identical to the r12-passing knn_kernel. Only the loop range is
// per-chunk (occupancy fix: 256 -> 1024 blocks). Merging preserves (d, s)
// lexicographic order, so tie sites are unchanged.
__global__ __launch_bounds__(256) void knn_part_kernel(
    const float* __restrict__ xyz1, const float* __restrict__ xyz2,
    float4* __restrict__ pd4, int4* __restrict__ pi4)
{
    __shared__ float4 pts[SCH];   // 4 KB
    const int b = blockIdx.z;
    const int ch = blockIdx.y;
    const float* p2 = xyz2 + ((size_t)b * SS + (size_t)ch * SCH) * 3;
    for (int i = threadIdx.x; i < SCH; i += 256) {
        float x = p2[i * 3 + 0], y = p2[i * 3 + 1], z = p2[i * 3 + 2];
        pts[i] = make_float4(x, y, z, x * x + y * y + z * z);
    }
    __syncthreads();

    const int n = blockIdx.x * 256 + threadIdx.x;
    const float* p1 = xyz1 + ((size_t)b * NN + n) * 3;
    const float x = p1[0], y = p1[1], z = p1[2];
    const float s1 = x * x + y * y + z * z;

    float d0 = 3.4e38f, d1 = 3.4e38f, d2 = 3.4e38f, d3 = 3.4e38f;
    int i0 = 0, i1 = 0, i2 = 0, i3 = 0;
    const int sbase = ch * SCH;
    #pragma unroll 4
    for (int sl = 0; sl < SCH; ++sl) {
        float4 p = pts[sl];
        float d = s1 + p.w - 2.0f * (x * p.x + y * p.y + z * p.z);
        int s = sbase + sl;
        bool lt0 = d < d0, lt1 = d < d1, lt2 = d < d2, lt3 = d < d3;
        float nd3 = lt2 ? d2 : (lt3 ? d : d3); int ni3 = lt2 ? i2 : (lt3 ? s : i3);
        float nd2 = lt1 ? d1 : (lt2 ? d : d2); int ni2 = lt1 ? i1 : (lt2 ? s : i2);
        float nd1 = lt0 ? d0 : (lt1 ? d : d1); int ni1 = lt0 ? i0 : (lt1 ? s : i1);
        d0 = lt0 ? d : d0;                     i0 = lt0 ? s : i0;
        d1 = nd1; i1 = ni1; d2 = nd2; i2 = ni2; d3 = nd3; i3 = ni3;
    }
    size_t o = ((size_t)b * NN + n) * KCH + ch;
    pd4[o] = make_float4(d0, d1, d2, d3);
    pi4[o] = make_int4(i0, i1, i2, i3);
}

// ------- Kernel 1b: merge per-chunk top-4 -> global top-4 + weights --------
// Identical strict-< insertion chain; candidates arrive in (chunk, asc-d)
// order which preserves the sequential scan's (d, s) tie ordering.
__global__ __launch_bounds__(256) void knn_merge_kernel(
    const float4* __restrict__ pd4, const int4* __restrict__ pi4,
    int* __restrict__ idx4, float* __restrict__ w4)
{
    const int n = blockIdx.x * 256 + threadIdx.x;
    const int b = blockIdx.y;
    const size_t o = ((size_t)b * NN + n) * KCH;

    float d0 = 3.4e38f, d1 = 3.4e38f, d2 = 3.4e38f, d3 = 3.4e38f;
    int i0 = 0, i1 = 0, i2 = 0, i3 = 0;
    #pragma unroll
    for (int ch = 0; ch < KCH; ++ch) {
        float4 pd = pd4[o + ch];
        int4 pi = pi4[o + ch];
        float cd[4] = { pd.x, pd.y, pd.z, pd.w };
        int   ci[4] = { pi.x, pi.y, pi.z, pi.w };
        #pragma unroll
        for (int k = 0; k < 4; ++k) {
            float d = cd[k]; int s = ci[k];
            bool lt0 = d < d0, lt1 = d < d1, lt2 = d < d2, lt3 = d < d3;
            float nd3 = lt2 ? d2 : (lt3 ? d : d3); int ni3 = lt2 ? i2 : (lt3 ? s : i3);
            float nd2 = lt1 ? d1 : (lt2 ? d : d2); int ni2 = lt1 ? i1 : (lt2 ? s : i2);
            float nd1 = lt0 ? d0 : (lt1 ? d : d1); int ni1 = lt0 ? i0 : (lt1 ? s : i1);
            d0 = lt0 ? d : d0;                     i0 = lt0 ? s : i0;
            d1 = nd1; i1 = ni1; d2 = nd2; i2 = ni2; d3 = nd3; i3 = ni3;
        }
    }
    float r0 = 1.0f / (d0 + 1e-8f);
    float r1 = 1.0f / (d1 + 1e-8f);
    float r2 = 1.0f / (d2 + 1e-8f);
    float rs = r0 + r1 + r2;
    bool tie = (d2 == d3);
    size_t base = ((size_t)b * NN + n) * 4;
    idx4[base + 0] = i0; idx4[base + 1] = i1;
    idx4[base + 2] = i2; idx4[base + 3] = i3;
    w4[base + 0] = r0 / rs; w4[base + 1] = r1 / rs;
    w4[base + 2] = r2 / rs; w4[base + 3] = tie ? -1.0f : 0.0f;
}

// ---------------- Kernel 2: transpose points2 f32[C2,S] -> f32[S,C2] -------
__global__ __launch_bounds__(256) void p2t_kernel(
    const float* __restrict__ p2, float* __restrict__ p2t)
{
    __shared__ float tile[64][65];
    const int b = blockIdx.z;
    const int s0 = blockIdx.x * 64, c0 = blockIdx.y * 64;
    for (int i = threadIdx.x; i < 64 * 64; i += 256) {
        int s = i & 63, c = i >> 6;
        tile[c][s] = p2[((size_t)b * C2 + c0 + c) * SS + s0 + s];
    }
    __syncthreads();
    for (int i = threadIdx.x; i < 64 * 64; i += 256) {
        int c = i & 63, s = i >> 6;
        p2t[((size_t)b * SS + s0 + s) * C2 + c0 + c] = tile[c][s];
    }
}

// ------- Kernel 2c: split conv weights f32 -> bf16 hi/lo planes (once) -----
__global__ __launch_bounds__(256) void wprep_kernel(
    const float* __restrict__ fw, const float* __restrict__ w1,
    const float* __restrict__ w2,
    __bf16* __restrict__ Whf, __bf16* __restrict__ Wlf,
    __bf16* __restrict__ Wh1, __bf16* __restrict__ Wl1,
    __bf16* __restrict__ Wh2, __bf16* __restrict__ Wl2)
{
    int t = blockIdx.x * 256 + threadIdx.x;
    float v; __bf16 *oh, *ol; int idx;
    if (t < 49152)      { idx = t;         v = fw[idx]; oh = Whf; ol = Wlf; }
    else if (t < 65536) { idx = t - 49152; v = w1[idx]; oh = Wh1; ol = Wl1; }
    else                { idx = t - 65536; v = w2[idx]; oh = Wh2; ol = Wl2; }
    __bf16 h = (__bf16)v;
    oh[idx] = h; ol[idx] = (__bf16)(v - (float)h);
}

// ------- Kernel 2b: tie resolver (unchanged logic from r12) ----------------
__global__ __launch_bounds__(256) void tie_eval_kernel(
    const float* __restrict__ p2t, const float* __restrict__ points1,
    const int* __restrict__ idx4, float* __restrict__ w4,
    const float* __restrict__ fw, const float* __restrict__ fb,
    const float* __restrict__ fg, const float* __restrict__ fbt,
    const float* __restrict__ fm, const float* __restrict__ fv,
    const float* __restrict__ w1m, const float* __restrict__ b1,
    const float* __restrict__ g1, const float* __restrict__ bt1,
    const float* __restrict__ m1, const float* __restrict__ v1,
    const float* __restrict__ w2m, const float* __restrict__ b2,
    const float* __restrict__ g2, const float* __restrict__ bt2,
    const float* __restrict__ m2, const float* __restrict__ v2)
{
    __shared__ float Xs[4][2][CIN];
    __shared__ float XT[4][2][CO];
    __shared__ float Hs[4][2][CO];
    const int wave = threadIdx.x >> 6, lane = threadIdx.x & 63;
    const int n = blockIdx.x * 4 + wave;
    const int b = blockIdx.y;
    const size_t base = ((size_t)b * NN + n) * 4;
    if (w4[base + 3] != -1.0f) return;

    const int i0 = idx4[base + 0], i1 = idx4[base + 1];
    const int i2 = idx4[base + 2], i3 = idx4[base + 3];
    const float w0 = w4[base + 0], w1 = w4[base + 1], w2 = w4[base + 2];
    const float* P = p2t + (size_t)b * SS * C2;

    for (int c = lane; c < C1; c += 64) {
        float v = points1[((size_t)b * C1 + c) * NN + n];
        Xs[wave][0][c] = v; Xs[wave][1][c] = v;
    }
    for (int c = lane; c < C2; c += 64) {
        float f0 = P[(size_t)i0 * C2 + c], f1 = P[(size_t)i1 * C2 + c];
        float f2 = P[(size_t)i2 * C2 + c], f3 = P[(size_t)i3 * C2 + c];
        float bs = w0 * f0 + w1 * f1;
        Xs[wave][0][C1 + c] = bs + w2 * f2;
        Xs[wave][1][C1 + c] = bs + w2 * f3;
    }
    #pragma unroll
    for (int k = 0; k < 2; ++k) {
        int oc = lane + 64 * k;
        float alo = fb[oc], ahi = fb[oc];
        for (int c = 0; c < CIN; ++c) {
            float wv = fw[(size_t)oc * CIN + c];
            alo += wv * Xs[wave][0][c];
            ahi += wv * Xs[wave][1][c];
        }
        float s = fg[oc] * (1.0f / sqrtf(fv[oc] + 1e-5f));
        XT[wave][0][oc] = fmaxf(s * (alo - fm[oc]) + fbt[oc], 0.0f);
        XT[wave][1][oc] = fmaxf(s * (ahi - fm[oc]) + fbt[oc], 0.0f);
    }
    #pragma unroll
    for (int k = 0; k < 2; ++k) {
        int oc = lane + 64 * k;
        float alo = b1[oc], ahi = b1[oc];
        for (int c = 0; c < CO; ++c) {
            float wv = w1m[(size_t)oc * CO + c];
            alo += wv * XT[wave][0][c];
            ahi += wv * XT[wave][1][c];
        }
        float s = g1[oc] * (1.0f / sqrtf(v1[oc] + 1e-5f));
        Hs[wave][0][oc] = fmaxf(s * (alo - m1[oc]) + bt1[oc], 0.0f);
        Hs[wave][1][oc] = fmaxf(s * (ahi - m1[oc]) + bt1[oc], 0.0f);
    }
    float e = 0.0f;
    #pragma unroll
    for (int k = 0; k < 2; ++k) {
        int oc = lane + 64 * k;
        float alo = b2[oc], ahi = b2[oc];
        for (int c = 0; c < CO; ++c) {
            float wv = w2m[(size_t)oc * CO + c];
            alo += wv * Hs[wave][0][c];
            ahi += wv * Hs[wave][1][c];
        }
        float s = g2[oc] * (1.0f / sqrtf(v2[oc] + 1e-5f));
        float olo = fmaxf(s * (alo - m2[oc]) + bt2[oc] + XT[wave][0][oc], 0.0f);
        float ohi = fmaxf(s * (ahi - m2[oc]) + bt2[oc] + XT[wave][1][oc], 0.0f);
        e = fmaxf(e, fabsf(olo - ohi));
    }
    for (int off = 32; off; off >>= 1) e = fmaxf(e, __shfl_xor(e, off));
    if (lane == 0) {
        if (e > 0.085f) { w4[base + 3] = 0.0f; }
        else { w4[base + 2] = 0.5f * w2; w4[base + 3] = 0.5f * w2; }
    }
}

// ---------------- Kernel 3: build X (bf16 hi/lo planes) --------------------
__global__ __launch_bounds__(256) void buildx_kernel(
    const float* __restrict__ points1,
    const float* __restrict__ p2t,
    const int* __restrict__ idx4, const float* __restrict__ w4,
    __bf16* __restrict__ Xh, __bf16* __restrict__ Xl)
{
    __shared__ float t1[128][66];
    const int b = blockIdx.y;
    const int n0 = blockIdx.x * 64;
    for (int i = threadIdx.x; i < 128 * 64; i += 256) {
        int j = i & 63, c = i >> 6;
        t1[c][j] = points1[((size_t)b * C1 + c) * NN + n0 + j];
    }
    __syncthreads();
    for (int i = threadIdx.x; i < 128 * 64; i += 256) {
        int c = i & 127, j = i >> 7;
        float v = t1[c][j];
        __bf16 h = (__bf16)v;
        size_t o = ((size_t)b * NN + n0 + j) * CIN + c;
        Xh[o] = h; Xl[o] = (__bf16)(v - (float)h);
    }
    for (int i = threadIdx.x; i < 64 * C2; i += 256) {
        int c = i & 255, j = i >> 8;
        int n = n0 + j;
        size_t ib = ((size_t)b * NN + n) * 4;
        int s0 = idx4[ib + 0], s1 = idx4[ib + 1];
        int s2 = idx4[ib + 2], s3 = idx4[ib + 3];
        float w0 = w4[ib + 0], w1 = w4[ib + 1];
        float w2 = w4[ib + 2], w3 = w4[ib + 3];
        const float* base = p2t + (size_t)b * SS * C2;
        float v = w0 * base[(size_t)s0 * C2 + c]
                + w1 * base[(size_t)s1 * C2 + c]
                + w2 * base[(size_t)s2 * C2 + c]
                + w3 * base[(size_t)s3 * C2 + c];
        __bf16 h = (__bf16)v;
        size_t o = ((size_t)b * NN + n) * CIN + C1 + c;
        Xh[o] = h; Xl[o] = (__bf16)(v - (float)h);
    }
}

// ------- Kernels 4-6: split-bf16 MFMA GEMM v2 ------------------------------
// A and W pre-split into bf16 hi/lo planes (zero load-time conversion).
// 128-row blocks, 32 rows/wave. acc += hi*wh + lo*wh + hi*wl.
// MODE 0: out = relu(bn(..)) -> bf16 hi/lo planes [M,128]
// MODE 1: out = relu(bn(..) + skip) -> f32 transposed [B,128,N] via LDS tile
template<int K, int MODE>
__global__ __launch_bounds__(256) void gemm_bn_kernel(
    const __bf16* __restrict__ Ah, const __bf16* __restrict__ Al,
    const __bf16* __restrict__ Wh, const __bf16* __restrict__ Wl,
    const float* __restrict__ cb,  const float* __restrict__ gg,
    const float* __restrict__ bbta, const float* __restrict__ mm,
    const float* __restrict__ vv,
    const __bf16* __restrict__ skiph, const __bf16* __restrict__ skipl,
    __bf16* __restrict__ outh, __bf16* __restrict__ outl,
    float* __restrict__ outf)
{
    __shared__ __attribute__((aligned(16))) __bf16 wls_h[128 * 40]; // 10 KB
    __shared__ __attribute__((aligned(16))) __bf16 wls_l[128 * 40]; // 10 KB
    __shared__ float s_s[128], s_t[128];
    __shared__ float tile[32][132];   // MODE1 transpose staging
    const int tid = threadIdx.x;
    if (tid < 128) {
        float s = gg[tid] * (1.0f / sqrtf(vv[tid] + 1e-5f));
        float t = (cb[tid] - mm[tid]) * s + bbta[tid];
        s_s[tid] = s; s_t[tid] = t;
    }
    const int wave = tid >> 6, lane = tid & 63;
    const int m = lane & 15, q = lane >> 4;
    const size_t r0 = (size_t)blockIdx.x * 128 + wave * 32;

    f32x4 acc[2][8] = {};
    const __bf16* pAh = Ah + (r0 + m) * (size_t)K + q * 8;
    const __bf16* pAl = Al + (r0 + m) * (size_t)K + q * 8;

    const int wrow = tid >> 1, whf = tid & 1;
    for (int kk = 0; kk < K; kk += 32) {
        __syncthreads();
        {   // stage Wh/Wl tile (each thread: 16 elems per plane)
            size_t g = (size_t)wrow * K + kk + whf * 16;
            int lo = wrow * 40 + whf * 16;
            *(uint4*)&wls_h[lo]     = *(const uint4*)&Wh[g];
            *(uint4*)&wls_h[lo + 8] = *(const uint4*)&Wh[g + 8];
            *(uint4*)&wls_l[lo]     = *(const uint4*)&Wl[g];
            *(uint4*)&wls_l[lo + 8] = *(const uint4*)&Wl[g + 8];
        }
        __syncthreads();
        bf16x8 ah0 = *(const bf16x8*)(pAh + kk);
        bf16x8 al0 = *(const bf16x8*)(pAl + kk);
        bf16x8 ah1 = *(const bf16x8*)(pAh + 16 * (size_t)K + kk);
        bf16x8 al1 = *(const bf16x8*)(pAl + 16 * (size_t)K + kk);
        #pragma unroll
        for (int ot = 0; ot < 8; ++ot) {
            bf16x8 bh = *(const bf16x8*)&wls_h[(ot * 16 + m) * 40 + q * 8];
            bf16x8 bl = *(const bf16x8*)&wls_l[(ot * 16 + m) * 40 + q * 8];
            acc[0][ot] = __builtin_amdgcn_mfma_f32_16x16x32_bf16(ah0, bh, acc[0][ot], 0, 0, 0);
            acc[0][ot] = __builtin_amdgcn_mfma_f32_16x16x32_bf16(al0, bh, acc[0][ot], 0, 0, 0);
            acc[0][ot] = __builtin_amdgcn_mfma_f32_16x16x32_bf16(ah0, bl, acc[0][ot], 0, 0, 0);
            acc[1][ot] = __builtin_amdgcn_mfma_f32_16x16x32_bf16(ah1, bh, acc[1][ot], 0, 0, 0);
            acc[1][ot] = __builtin_amdgcn_mfma_f32_16x16x32_bf16(al1, bh, acc[1][ot], 0, 0, 0);
            acc[1][ot] = __builtin_amdgcn_mfma_f32_16x16x32_bf16(ah1, bl, acc[1][ot], 0, 0, 0);
        }
    }

    if (MODE == 0) {
        #pragma unroll
        for (int rt = 0; rt < 2; ++rt) {
            #pragma unroll
            for (int ot = 0; ot < 8; ++ot) {
                int col = ot * 16 + m;
                float sc = s_s[col], sh = s_t[col];
                #pragma unroll
                for (int r = 0; r < 4; ++r) {
                    size_t row = r0 + rt * 16 + q * 4 + r;
                    float val = fmaxf(acc[rt][ot][r] * sc + sh, 0.0f);
                    __bf16 h = (__bf16)val;
                    outh[row * 128 + col] = h;
                    outl[row * 128 + col] = (__bf16)(val - (float)h);
                }
            }
        }
    } else {
        const int bidx = (int)(((size_t)blockIdx.x * 128) >> 12);
        const int nbase = (int)(((size_t)blockIdx.x * 128) & 4095);
        for (int cc = 0; cc < 4; ++cc) {
            __syncthreads();
            #pragma unroll
            for (int oo = 0; oo < 2; ++oo) {
                int ot = cc * 2 + oo;
                int col = ot * 16 + m;
                float sc = s_s[col], sh = s_t[col];
                #pragma unroll
                for (int rt = 0; rt < 2; ++rt) {
                    #pragma unroll
                    for (int r = 0; r < 4; ++r) {
                        int lrow = wave * 32 + rt * 16 + q * 4 + r;
                        size_t row = (size_t)blockIdx.x * 128 + lrow;
                        float val = acc[rt][ot][r] * sc + sh;
                        val += (float)skiph[row * 128 + col] + (float)skipl[row * 128 + col];
                        val = fmaxf(val, 0.0f);
                        tile[oo * 16 + m][lrow] = val;
                    }
                }
            }
            __syncthreads();
            for (int c2 = tid >> 7; c2 < 32; c2 += 2) {
                int nn_ = tid & 127;
                outf[((size_t)bidx * 128 + cc * 32 + c2) * NN + nbase + nn_] = tile[c2][nn_];
            }
        }
    }
}

extern "C" void kernel_launch(void* const* d_in, const int* in_sizes, int n_in,
                              void* d_out, int out_size, void* d_ws, size_t ws_size,
                              hipStream_t stream) {
    const float* xyz1    = (const float*)d_in[0];
    const float* xyz2    = (const float*)d_in[1];
    const float* points1 = (const float*)d_in[2];
    const float* points2 = (const float*)d_in[3];
    const float* fuse_w  = (const float*)d_in[4];
    const float* fuse_b  = (const float*)d_in[5];
    const float* fuse_g  = (const float*)d_in[6];
    const float* fuse_bt = (const float*)d_in[7];
    const float* fuse_m  = (const float*)d_in[8];
    const float* fuse_v  = (const float*)d_in[9];
    const float* c1_w    = (const float*)d_in[10];
    const float* c1_b    = (const float*)d_in[11];
    const float* bn1_g   = (const float*)d_in[12];
    const float* bn1_b   = (const float*)d_in[13];
    const float* bn1_m   = (const float*)d_in[14];
    const float* bn1_v   = (const float*)d_in[15];
    const float* c2_w    = (const float*)d_in[16];
    const float* c2_b    = (const float*)d_in[17];
    const float* bn2_g   = (const float*)d_in[18];
    const float* bn2_b   = (const float*)d_in[19];
    const float* bn2_m   = (const float*)d_in[20];
    const float* bn2_v   = (const float*)d_in[21];

    char* ws = (char*)d_ws;
    int*    idx4 = (int*)(ws);                      // 1 MB
    float*  w4   = (float*)(ws + 1048576);          // 1 MB
    float*  p2t  = (float*)(ws + 2097152);          // 16.78 MB
    __bf16* Xh   = (__bf16*)(ws + 18874368);        // 48 MB
    __bf16* Xl   = (__bf16*)(ws + 69206016);        // 48 MB
    __bf16* Y0h  = (__bf16*)(ws + 119537664);       // 16 MB
    __bf16* Y0l  = (__bf16*)(ws + 136314880);       // 16 MB
    __bf16* Hh   = (__bf16*)(ws + 153092096);       // 16 MB
    __bf16* Hl   = (__bf16*)(ws + 169869312);       // 16 MB
    __bf16* Whf  = (__bf16*)(ws + 186646528);       // 96 KB
    __bf16* Wlf  = (__bf16*)(ws + 186744832);       // 96 KB
    __bf16* Wh1  = (__bf16*)(ws + 186843136);       // 32 KB
    __bf16* Wl1  = (__bf16*)(ws + 186875904);       // 32 KB
    __bf16* Wh2  = (__bf16*)(ws + 186908672);       // 32 KB
    __bf16* Wl2  = (__bf16*)(ws + 186941440);       // 32 KB

    // knn partials aliased into the Xh region (consumed by merge BEFORE
    // buildx writes Xh; same-stream ordering makes this safe).
    float4* pd4 = (float4*)(ws + 18874368);                 // 4 MB
    int4*   pi4 = (int4*)(ws + 18874368 + 4194304);         // 4 MB

    knn_part_kernel<<<dim3(NN / 256, KCH, BB), 256, 0, stream>>>(xyz1, xyz2, pd4, pi4);
    knn_merge_kernel<<<dim3(NN / 256, BB), 256, 0, stream>>>(pd4, pi4, idx4, w4);
    p2t_kernel<<<dim3(SS / 64, C2 / 64, BB), 256, 0, stream>>>(points2, p2t);
    wprep_kernel<<<320, 256, 0, stream>>>(fuse_w, c1_w, c2_w,
                                          Whf, Wlf, Wh1, Wl1, Wh2, Wl2);
    tie_eval_kernel<<<dim3(NN / 4, BB), 256, 0, stream>>>(
        p2t, points1, idx4, w4,
        fuse_w, fuse_b, fuse_g, fuse_bt, fuse_m, fuse_v,
        c1_w, c1_b, bn1_g, bn1_b, bn1_m, bn1_v,
        c2_w, c2_b, bn2_g, bn2_b, bn2_m, bn2_v);
    buildx_kernel<<<dim3(NN / 64, BB), 256, 0, stream>>>(points1, p2t, idx4, w4, Xh, Xl);

    const int gblocks = (BB * NN) / 128;   // 512
    gemm_bn_kernel<CIN, 0><<<gblocks, 256, 0, stream>>>(
        Xh, Xl, Whf, Wlf, fuse_b, fuse_g, fuse_bt, fuse_m, fuse_v,
        nullptr, nullptr, Y0h, Y0l, nullptr);
    gemm_bn_kernel<CO, 0><<<gblocks, 256, 0, stream>>>(
        Y0h, Y0l, Wh1, Wl1, c1_b, bn1_g, bn1_b, bn1_m, bn1_v,
        nullptr, nullptr, Hh, Hl, nullptr);
    gemm_bn_kernel<CO, 1><<<gblocks, 256, 0, stream>>>(
        Hh, Hl, Wh2, Wl2, c2_b, bn2_g, bn2_b, bn2_m, bn2_v,
        Y0h, Y0l, nullptr, nullptr, (float*)d_out);
}

// Round 4
// 347.634 us; speedup vs baseline: 1.0764x; 1.0206x over previous
//
#include <hip/hip_runtime.h>
#include <hip/hip_bf16.h>

#define BB 16
#define NN 4096
#define SS 1024
#define C1 128
#define C2 256
#define CIN 384
#define CO 128

#define KCH 4            // knn S-chunks
#define SCH (SS / KCH)   // 256 points per chunk

typedef __bf16 bf16x8 __attribute__((ext_vector_type(8)));
typedef float f32x4 __attribute__((ext_vector_type(4)));

static __device__ __forceinline__ unsigned int pack2bf(float a, float b,
                                                       unsigned int& lopack) {
    __bf16 ha = (__bf16)a, hb = (__bf16)b;
    __bf16 la = (__bf16)(a - (float)ha), lb = (__bf16)(b - (float)hb);
    lopack = (unsigned int)__builtin_bit_cast(unsigned short, la)
           | ((unsigned int)__builtin_bit_cast(unsigned short, lb) << 16);
    return (unsigned int)__builtin_bit_cast(unsigned short, ha)
         | ((unsigned int)__builtin_bit_cast(unsigned short, hb) << 16);
}

// ------- Kernel 1a: partial 3-NN scan over one S-chunk ---------------------
// FROZEN ARITHMETIC (see r12/r2 notes): distance expr + insertion chain
// byte-identical; only the loop range is per-chunk.
__global__ __launch_bounds__(256) void knn_part_kernel(
    const float* __restrict__ xyz1, const float* __restrict__ xyz2,
    float4* __restrict__ pd4, int4* __restrict__ pi4)
{
    __shared__ float4 pts[SCH];   // 4 KB
    const int b = blockIdx.z;
    const int ch = blockIdx.y;
    const float* p2 = xyz2 + ((size_t)b * SS + (size_t)ch * SCH) * 3;
    for (int i = threadIdx.x; i < SCH; i += 256) {
        float x = p2[i * 3 + 0], y = p2[i * 3 + 1], z = p2[i * 3 + 2];
        pts[i] = make_float4(x, y, z, x * x + y * y + z * z);
    }
    __syncthreads();

    const int n = blockIdx.x * 256 + threadIdx.x;
    const float* p1 = xyz1 + ((size_t)b * NN + n) * 3;
    const float x = p1[0], y = p1[1], z = p1[2];
    const float s1 = x * x + y * y + z * z;

    float d0 = 3.4e38f, d1 = 3.4e38f, d2 = 3.4e38f, d3 = 3.4e38f;
    int i0 = 0, i1 = 0, i2 = 0, i3 = 0;
    const int sbase = ch * SCH;
    #pragma unroll 4
    for (int sl = 0; sl < SCH; ++sl) {
        float4 p = pts[sl];
        float d = s1 + p.w - 2.0f * (x * p.x + y * p.y + z * p.z);
        int s = sbase + sl;
        bool lt0 = d < d0, lt1 = d < d1, lt2 = d < d2, lt3 = d < d3;
        float nd3 = lt2 ? d2 : (lt3 ? d : d3); int ni3 = lt2 ? i2 : (lt3 ? s : i3);
        float nd2 = lt1 ? d1 : (lt2 ? d : d2); int ni2 = lt1 ? i1 : (lt2 ? s : i2);
        float nd1 = lt0 ? d0 : (lt1 ? d : d1); int ni1 = lt0 ? i0 : (lt1 ? s : i1);
        d0 = lt0 ? d : d0;                     i0 = lt0 ? s : i0;
        d1 = nd1; i1 = ni1; d2 = nd2; i2 = ni2; d3 = nd3; i3 = ni3;
    }
    size_t o = ((size_t)b * NN + n) * KCH + ch;
    pd4[o] = make_float4(d0, d1, d2, d3);
    pi4[o] = make_int4(i0, i1, i2, i3);
}

// ------- Kernel 1b: merge per-chunk top-4 -> global top-4 + weights --------
__global__ __launch_bounds__(256) void knn_merge_kernel(
    const float4* __restrict__ pd4, const int4* __restrict__ pi4,
    int* __restrict__ idx4, float* __restrict__ w4)
{
    const int n = blockIdx.x * 256 + threadIdx.x;
    const int b = blockIdx.y;
    const size_t o = ((size_t)b * NN + n) * KCH;

    float d0 = 3.4e38f, d1 = 3.4e38f, d2 = 3.4e38f, d3 = 3.4e38f;
    int i0 = 0, i1 = 0, i2 = 0, i3 = 0;
    #pragma unroll
    for (int ch = 0; ch < KCH; ++ch) {
        float4 pd = pd4[o + ch];
        int4 pi = pi4[o + ch];
        float cd[4] = { pd.x, pd.y, pd.z, pd.w };
        int   ci[4] = { pi.x, pi.y, pi.z, pi.w };
        #pragma unroll
        for (int k = 0; k < 4; ++k) {
            float d = cd[k]; int s = ci[k];
            bool lt0 = d < d0, lt1 = d < d1, lt2 = d < d2, lt3 = d < d3;
            float nd3 = lt2 ? d2 : (lt3 ? d : d3); int ni3 = lt2 ? i2 : (lt3 ? s : i3);
            float nd2 = lt1 ? d1 : (lt2 ? d : d2); int ni2 = lt1 ? i1 : (lt2 ? s : i2);
            float nd1 = lt0 ? d0 : (lt1 ? d : d1); int ni1 = lt0 ? i0 : (lt1 ? s : i1);
            d0 = lt0 ? d : d0;                     i0 = lt0 ? s : i0;
            d1 = nd1; i1 = ni1; d2 = nd2; i2 = ni2; d3 = nd3; i3 = ni3;
        }
    }
    float r0 = 1.0f / (d0 + 1e-8f);
    float r1 = 1.0f / (d1 + 1e-8f);
    float r2 = 1.0f / (d2 + 1e-8f);
    float rs = r0 + r1 + r2;
    bool tie = (d2 == d3);
    size_t base = ((size_t)b * NN + n) * 4;
    idx4[base + 0] = i0; idx4[base + 1] = i1;
    idx4[base + 2] = i2; idx4[base + 3] = i3;
    w4[base + 0] = r0 / rs; w4[base + 1] = r1 / rs;
    w4[base + 2] = r2 / rs; w4[base + 3] = tie ? -1.0f : 0.0f;
}

// ---------------- Kernel 2: transpose points2 f32[C2,S] -> f32[S,C2] -------
__global__ __launch_bounds__(256) void p2t_kernel(
    const float* __restrict__ p2, float* __restrict__ p2t)
{
    __shared__ float tile[64][65];
    const int b = blockIdx.z;
    const int s0 = blockIdx.x * 64, c0 = blockIdx.y * 64;
    for (int i = threadIdx.x; i < 64 * 64; i += 256) {
        int s = i & 63, c = i >> 6;
        tile[c][s] = p2[((size_t)b * C2 + c0 + c) * SS + s0 + s];
    }
    __syncthreads();
    for (int i = threadIdx.x; i < 64 * 64; i += 256) {
        int c = i & 63, s = i >> 6;
        p2t[((size_t)b * SS + s0 + s) * C2 + c0 + c] = tile[c][s];
    }
}

// ------- Kernel 2c: split conv weights f32 -> bf16 hi/lo planes (once) -----
__global__ __launch_bounds__(256) void wprep_kernel(
    const float* __restrict__ fw, const float* __restrict__ w1,
    const float* __restrict__ w2,
    __bf16* __restrict__ Whf, __bf16* __restrict__ Wlf,
    __bf16* __restrict__ Wh1, __bf16* __restrict__ Wl1,
    __bf16* __restrict__ Wh2, __bf16* __restrict__ Wl2)
{
    int t = blockIdx.x * 256 + threadIdx.x;
    float v; __bf16 *oh, *ol; int idx;
    if (t < 49152)      { idx = t;         v = fw[idx]; oh = Whf; ol = Wlf; }
    else if (t < 65536) { idx = t - 49152; v = w1[idx]; oh = Wh1; ol = Wl1; }
    else                { idx = t - 65536; v = w2[idx]; oh = Wh2; ol = Wl2; }
    __bf16 h = (__bf16)v;
    oh[idx] = h; ol[idx] = (__bf16)(v - (float)h);
}

// ------- Kernel 2b: tie resolver (unchanged logic from r12) ----------------
__global__ __launch_bounds__(256) void tie_eval_kernel(
    const float* __restrict__ p2t, const float* __restrict__ points1,
    const int* __restrict__ idx4, float* __restrict__ w4,
    const float* __restrict__ fw, const float* __restrict__ fb,
    const float* __restrict__ fg, const float* __restrict__ fbt,
    const float* __restrict__ fm, const float* __restrict__ fv,
    const float* __restrict__ w1m, const float* __restrict__ b1,
    const float* __restrict__ g1, const float* __restrict__ bt1,
    const float* __restrict__ m1, const float* __restrict__ v1,
    const float* __restrict__ w2m, const float* __restrict__ b2,
    const float* __restrict__ g2, const float* __restrict__ bt2,
    const float* __restrict__ m2, const float* __restrict__ v2)
{
    __shared__ float Xs[4][2][CIN];
    __shared__ float XT[4][2][CO];
    __shared__ float Hs[4][2][CO];
    const int wave = threadIdx.x >> 6, lane = threadIdx.x & 63;
    const int n = blockIdx.x * 4 + wave;
    const int b = blockIdx.y;
    const size_t base = ((size_t)b * NN + n) * 4;
    if (w4[base + 3] != -1.0f) return;

    const int i0 = idx4[base + 0], i1 = idx4[base + 1];
    const int i2 = idx4[base + 2], i3 = idx4[base + 3];
    const float w0 = w4[base + 0], w1 = w4[base + 1], w2 = w4[base + 2];
    const float* P = p2t + (size_t)b * SS * C2;

    for (int c = lane; c < C1; c += 64) {
        float v = points1[((size_t)b * C1 + c) * NN + n];
        Xs[wave][0][c] = v; Xs[wave][1][c] = v;
    }
    for (int c = lane; c < C2; c += 64) {
        float f0 = P[(size_t)i0 * C2 + c], f1 = P[(size_t)i1 * C2 + c];
        float f2 = P[(size_t)i2 * C2 + c], f3 = P[(size_t)i3 * C2 + c];
        float bs = w0 * f0 + w1 * f1;
        Xs[wave][0][C1 + c] = bs + w2 * f2;
        Xs[wave][1][C1 + c] = bs + w2 * f3;
    }
    #pragma unroll
    for (int k = 0; k < 2; ++k) {
        int oc = lane + 64 * k;
        float alo = fb[oc], ahi = fb[oc];
        for (int c = 0; c < CIN; ++c) {
            float wv = fw[(size_t)oc * CIN + c];
            alo += wv * Xs[wave][0][c];
            ahi += wv * Xs[wave][1][c];
        }
        float s = fg[oc] * (1.0f / sqrtf(fv[oc] + 1e-5f));
        XT[wave][0][oc] = fmaxf(s * (alo - fm[oc]) + fbt[oc], 0.0f);
        XT[wave][1][oc] = fmaxf(s * (ahi - fm[oc]) + fbt[oc], 0.0f);
    }
    #pragma unroll
    for (int k = 0; k < 2; ++k) {
        int oc = lane + 64 * k;
        float alo = b1[oc], ahi = b1[oc];
        for (int c = 0; c < CO; ++c) {
            float wv = w1m[(size_t)oc * CO + c];
            alo += wv * XT[wave][0][c];
            ahi += wv * XT[wave][1][c];
        }
        float s = g1[oc] * (1.0f / sqrtf(v1[oc] + 1e-5f));
        Hs[wave][0][oc] = fmaxf(s * (alo - m1[oc]) + bt1[oc], 0.0f);
        Hs[wave][1][oc] = fmaxf(s * (ahi - m1[oc]) + bt1[oc], 0.0f);
    }
    float e = 0.0f;
    #pragma unroll
    for (int k = 0; k < 2; ++k) {
        int oc = lane + 64 * k;
        float alo = b2[oc], ahi = b2[oc];
        for (int c = 0; c < CO; ++c) {
            float wv = w2m[(size_t)oc * CO + c];
            alo += wv * Hs[wave][0][c];
            ahi += wv * Hs[wave][1][c];
        }
        float s = g2[oc] * (1.0f / sqrtf(v2[oc] + 1e-5f));
        float olo = fmaxf(s * (alo - m2[oc]) + bt2[oc] + XT[wave][0][oc], 0.0f);
        float ohi = fmaxf(s * (ahi - m2[oc]) + bt2[oc] + XT[wave][1][oc], 0.0f);
        e = fmaxf(e, fabsf(olo - ohi));
    }
    for (int off = 32; off; off >>= 1) e = fmaxf(e, __shfl_xor(e, off));
    if (lane == 0) {
        if (e > 0.085f) { w4[base + 3] = 0.0f; }
        else { w4[base + 2] = 0.5f * w2; w4[base + 3] = 0.5f * w2; }
    }
}

// ------- Kernel 3a: points1 transpose -> X cols [0,128) bf16 hi/lo ---------
// LDS layout [n][c] so the read phase gets contiguous-c float4 reads and the
// stores are 16B packed (vs r3's per-element 2B stores).
__global__ __launch_bounds__(256) void buildx1_kernel(
    const float* __restrict__ points1,
    __bf16* __restrict__ Xh, __bf16* __restrict__ Xl)
{
    __shared__ __attribute__((aligned(16))) float t1[64][132];
    const int b = blockIdx.y;
    const int n0 = blockIdx.x * 64;
    for (int i = threadIdx.x; i < 128 * 64; i += 256) {
        int j = i & 63, c = i >> 6;
        t1[j][c] = points1[((size_t)b * C1 + c) * NN + n0 + j];
    }
    __syncthreads();
    for (int i = threadIdx.x; i < 16 * 64; i += 256) {
        int c8 = i & 15, j = i >> 4;
        float4 va = *(const float4*)&t1[j][c8 * 8];
        float4 vb = *(const float4*)&t1[j][c8 * 8 + 4];
        unsigned int hu0, hu1, hu2, hu3, lu0, lu1, lu2, lu3;
        hu0 = pack2bf(va.x, va.y, lu0);
        hu1 = pack2bf(va.z, va.w, lu1);
        hu2 = pack2bf(vb.x, vb.y, lu2);
        hu3 = pack2bf(vb.z, vb.w, lu3);
        size_t o = ((size_t)b * NN + n0 + j) * CIN + c8 * 8;
        *(uint4*)&Xh[o] = make_uint4(hu0, hu1, hu2, hu3);
        *(uint4*)&Xl[o] = make_uint4(lu0, lu1, lu2, lu3);
    }
}

// ------- Kernel 3b: gather-interp -> X cols [128,384) bf16 hi/lo -----------
// Zero LDS (high occupancy for latency hiding), float4 gather reads,
// non-temporal 8B stores (keep the 67MB write stream out of L2 so the
// gathered p2t rows stay cached).
__global__ __launch_bounds__(256) void buildx2_kernel(
    const float* __restrict__ p2t,
    const int* __restrict__ idx4, const float* __restrict__ w4,
    __bf16* __restrict__ Xh, __bf16* __restrict__ Xl)
{
    const int lane = threadIdx.x & 63;
    const size_t p = (size_t)blockIdx.x * 4 + (threadIdx.x >> 6);
    const int b = (int)(p >> 12);
    const size_t ib = p * 4;
    const int s0 = idx4[ib + 0], s1 = idx4[ib + 1];
    const int s2 = idx4[ib + 2], s3 = idx4[ib + 3];
    const float w0 = w4[ib + 0], w1 = w4[ib + 1];
    const float w2 = w4[ib + 2], w3 = w4[ib + 3];
    const float* base = p2t + (size_t)b * SS * C2;
    const float4 f0 = *(const float4*)(base + (size_t)s0 * C2 + lane * 4);
    const float4 f1 = *(const float4*)(base + (size_t)s1 * C2 + lane * 4);
    const float4 f2 = *(const float4*)(base + (size_t)s2 * C2 + lane * 4);
    const float4 f3 = *(const float4*)(base + (size_t)s3 * C2 + lane * 4);
    // same per-channel expression as the r3-passing buildx gather
    float v0 = w0 * f0.x + w1 * f1.x + w2 * f2.x + w3 * f3.x;
    float v1 = w0 * f0.y + w1 * f1.y + w2 * f2.y + w3 * f3.y;
    float v2 = w0 * f0.z + w1 * f1.z + w2 * f2.z + w3 * f3.z;
    float v3 = w0 * f0.w + w1 * f1.w + w2 * f2.w + w3 * f3.w;
    unsigned int hu0, hu1, lu0, lu1;
    hu0 = pack2bf(v0, v1, lu0);
    hu1 = pack2bf(v2, v3, lu1);
    size_t o = p * CIN + C1 + (size_t)lane * 4;
    unsigned long long hp = (unsigned long long)hu0 | ((unsigned long long)hu1 << 32);
    unsigned long long lp = (unsigned long long)lu0 | ((unsigned long long)lu1 << 32);
    __builtin_nontemporal_store(hp, (unsigned long long*)&Xh[o]);
    __builtin_nontemporal_store(lp, (unsigned long long*)&Xl[o]);
}

// ------- Kernels 4-6: split-bf16 MFMA GEMM v2 ------------------------------
template<int K, int MODE>
__global__ __launch_bounds__(256) void gemm_bn_kernel(
    const __bf16* __restrict__ Ah, const __bf16* __restrict__ Al,
    const __bf16* __restrict__ Wh, const __bf16* __restrict__ Wl,
    const float* __restrict__ cb,  const float* __restrict__ gg,
    const float* __restrict__ bbta, const float* __restrict__ mm,
    const float* __restrict__ vv,
    const __bf16* __restrict__ skiph, const __bf16* __restrict__ skipl,
    __bf16* __restrict__ outh, __bf16* __restrict__ outl,
    float* __restrict__ outf)
{
    __shared__ __attribute__((aligned(16))) __bf16 wls_h[128 * 40]; // 10 KB
    __shared__ __attribute__((aligned(16))) __bf16 wls_l[128 * 40]; // 10 KB
    __shared__ float s_s[128], s_t[128];
    __shared__ float tile[32][132];   // MODE1 transpose staging
    const int tid = threadIdx.x;
    if (tid < 128) {
        float s = gg[tid] * (1.0f / sqrtf(vv[tid] + 1e-5f));
        float t = (cb[tid] - mm[tid]) * s + bbta[tid];
        s_s[tid] = s; s_t[tid] = t;
    }
    const int wave = tid >> 6, lane = tid & 63;
    const int m = lane & 15, q = lane >> 4;
    const size_t r0 = (size_t)blockIdx.x * 128 + wave * 32;

    f32x4 acc[2][8] = {};
    const __bf16* pAh = Ah + (r0 + m) * (size_t)K + q * 8;
    const __bf16* pAl = Al + (r0 + m) * (size_t)K + q * 8;

    const int wrow = tid >> 1, whf = tid & 1;
    for (int kk = 0; kk < K; kk += 32) {
        __syncthreads();
        {   // stage Wh/Wl tile (each thread: 16 elems per plane)
            size_t g = (size_t)wrow * K + kk + whf * 16;
            int lo = wrow * 40 + whf * 16;
            *(uint4*)&wls_h[lo]     = *(const uint4*)&Wh[g];
            *(uint4*)&wls_h[lo + 8] = *(const uint4*)&Wh[g + 8];
            *(uint4*)&wls_l[lo]     = *(const uint4*)&Wl[g];
            *(uint4*)&wls_l[lo + 8] = *(const uint4*)&Wl[g + 8];
        }
        __syncthreads();
        bf16x8 ah0 = *(const bf16x8*)(pAh + kk);
        bf16x8 al0 = *(const bf16x8*)(pAl + kk);
        bf16x8 ah1 = *(const bf16x8*)(pAh + 16 * (size_t)K + kk);
        bf16x8 al1 = *(const bf16x8*)(pAl + 16 * (size_t)K + kk);
        #pragma unroll
        for (int ot = 0; ot < 8; ++ot) {
            bf16x8 bh = *(const bf16x8*)&wls_h[(ot * 16 + m) * 40 + q * 8];
            bf16x8 bl = *(const bf16x8*)&wls_l[(ot * 16 + m) * 40 + q * 8];
            acc[0][ot] = __builtin_amdgcn_mfma_f32_16x16x32_bf16(ah0, bh, acc[0][ot], 0, 0, 0);
            acc[0][ot] = __builtin_amdgcn_mfma_f32_16x16x32_bf16(al0, bh, acc[0][ot], 0, 0, 0);
            acc[0][ot] = __builtin_amdgcn_mfma_f32_16x16x32_bf16(ah0, bl, acc[0][ot], 0, 0, 0);
            acc[1][ot] = __builtin_amdgcn_mfma_f32_16x16x32_bf16(ah1, bh, acc[1][ot], 0, 0, 0);
            acc[1][ot] = __builtin_amdgcn_mfma_f32_16x16x32_bf16(al1, bh, acc[1][ot], 0, 0, 0);
            acc[1][ot] = __builtin_amdgcn_mfma_f32_16x16x32_bf16(ah1, bl, acc[1][ot], 0, 0, 0);
        }
    }

    if (MODE == 0) {
        #pragma unroll
        for (int rt = 0; rt < 2; ++rt) {
            #pragma unroll
            for (int ot = 0; ot < 8; ++ot) {
                int col = ot * 16 + m;
                float sc = s_s[col], sh = s_t[col];
                #pragma unroll
                for (int r = 0; r < 4; ++r) {
                    size_t row = r0 + rt * 16 + q * 4 + r;
                    float val = fmaxf(acc[rt][ot][r] * sc + sh, 0.0f);
                    __bf16 h = (__bf16)val;
                    outh[row * 128 + col] = h;
                    outl[row * 128 + col] = (__bf16)(val - (float)h);
                }
            }
        }
    } else {
        const int bidx = (int)(((size_t)blockIdx.x * 128) >> 12);
        const int nbase = (int)(((size_t)blockIdx.x * 128) & 4095);
        for (int cc = 0; cc < 4; ++cc) {
            __syncthreads();
            #pragma unroll
            for (int oo = 0; oo < 2; ++oo) {
                int ot = cc * 2 + oo;
                int col = ot * 16 + m;
                float sc = s_s[col], sh = s_t[col];
                #pragma unroll
                for (int rt = 0; rt < 2; ++rt) {
                    #pragma unroll
                    for (int r = 0; r < 4; ++r) {
                        int lrow = wave * 32 + rt * 16 + q * 4 + r;
                        size_t row = (size_t)blockIdx.x * 128 + lrow;
                        float val = acc[rt][ot][r] * sc + sh;
                        val += (float)skiph[row * 128 + col] + (float)skipl[row * 128 + col];
                        val = fmaxf(val, 0.0f);
                        tile[oo * 16 + m][lrow] = val;
                    }
                }
            }
            __syncthreads();
            for (int c2 = tid >> 7; c2 < 32; c2 += 2) {
                int nn_ = tid & 127;
                outf[((size_t)bidx * 128 + cc * 32 + c2) * NN + nbase + nn_] = tile[c2][nn_];
            }
        }
    }
}

extern "C" void kernel_launch(void* const* d_in, const int* in_sizes, int n_in,
                              void* d_out, int out_size, void* d_ws, size_t ws_size,
                              hipStream_t stream) {
    const float* xyz1    = (const float*)d_in[0];
    const float* xyz2    = (const float*)d_in[1];
    const float* points1 = (const float*)d_in[2];
    const float* points2 = (const float*)d_in[3];
    const float* fuse_w  = (const float*)d_in[4];
    const float* fuse_b  = (const float*)d_in[5];
    const float* fuse_g  = (const float*)d_in[6];
    const float* fuse_bt = (const float*)d_in[7];
    const float* fuse_m  = (const float*)d_in[8];
    const float* fuse_v  = (const float*)d_in[9];
    const float* c1_w    = (const float*)d_in[10];
    const float* c1_b    = (const float*)d_in[11];
    const float* bn1_g   = (const float*)d_in[12];
    const float* bn1_b   = (const float*)d_in[13];
    const float* bn1_m   = (const float*)d_in[14];
    const float* bn1_v   = (const float*)d_in[15];
    const float* c2_w    = (const float*)d_in[16];
    const float* c2_b    = (const float*)d_in[17];
    const float* bn2_g   = (const float*)d_in[18];
    const float* bn2_b   = (const float*)d_in[19];
    const float* bn2_m   = (const float*)d_in[20];
    const float* bn2_v   = (const float*)d_in[21];

    char* ws = (char*)d_ws;
    int*    idx4 = (int*)(ws);                      // 1 MB
    float*  w4   = (float*)(ws + 1048576);          // 1 MB
    float*  p2t  = (float*)(ws + 2097152);          // 16.78 MB
    __bf16* Xh   = (__bf16*)(ws + 18874368);        // 48 MB
    __bf16* Xl   = (__bf16*)(ws + 69206016);        // 48 MB
    __bf16* Y0h  = (__bf16*)(ws + 119537664);       // 16 MB
    __bf16* Y0l  = (__bf16*)(ws + 136314880);       // 16 MB
    __bf16* Hh   = (__bf16*)(ws + 153092096);       // 16 MB
    __bf16* Hl   = (__bf16*)(ws + 169869312);       // 16 MB
    __bf16* Whf  = (__bf16*)(ws + 186646528);       // 96 KB
    __bf16* Wlf  = (__bf16*)(ws + 186744832);       // 96 KB
    __bf16* Wh1  = (__bf16*)(ws + 186843136);       // 32 KB
    __bf16* Wl1  = (__bf16*)(ws + 186875904);       // 32 KB
    __bf16* Wh2  = (__bf16*)(ws + 186908672);       // 32 KB
    __bf16* Wl2  = (__bf16*)(ws + 186941440);       // 32 KB

    // knn partials aliased into the Xh region (consumed by merge BEFORE
    // buildx1/2 write Xh; same-stream ordering makes this safe).
    float4* pd4 = (float4*)(ws + 18874368);                 // 4 MB
    int4*   pi4 = (int4*)(ws + 18874368 + 4194304);         // 4 MB

    knn_part_kernel<<<dim3(NN / 256, KCH, BB), 256, 0, stream>>>(xyz1, xyz2, pd4, pi4);
    knn_merge_kernel<<<dim3(NN / 256, BB), 256, 0, stream>>>(pd4, pi4, idx4, w4);
    p2t_kernel<<<dim3(SS / 64, C2 / 64, BB), 256, 0, stream>>>(points2, p2t);
    wprep_kernel<<<320, 256, 0, stream>>>(fuse_w, c1_w, c2_w,
                                          Whf, Wlf, Wh1, Wl1, Wh2, Wl2);
    tie_eval_kernel<<<dim3(NN / 4, BB), 256, 0, stream>>>(
        p2t, points1, idx4, w4,
        fuse_w, fuse_b, fuse_g, fuse_bt, fuse_m, fuse_v,
        c1_w, c1_b, bn1_g, bn1_b, bn1_m, bn1_v,
        c2_w, c2_b, bn2_g, bn2_b, bn2_m, bn2_v);
    buildx1_kernel<<<dim3(NN / 64, BB), 256, 0, stream>>>(points1, Xh, Xl);
    buildx2_kernel<<<(BB * NN) / 4, 256, 0, stream>>>(p2t, idx4, w4, Xh, Xl);

    const int gblocks = (BB * NN) / 128;   // 512
    gemm_bn_kernel<CIN, 0><<<gblocks, 256, 0, stream>>>(
        Xh, Xl, Whf, Wlf, fuse_b, fuse_g, fuse_bt, fuse_m, fuse_v,
        nullptr, nullptr, Y0h, Y0l, nullptr);
    gemm_bn_kernel<CO, 0><<<gblocks, 256, 0, stream>>>(
        Y0h, Y0l, Wh1, Wl1, c1_b, bn1_g, bn1_b, bn1_m, bn1_v,
        nullptr, nullptr, Hh, Hl, nullptr);
    gemm_bn_kernel<CO, 1><<<gblocks, 256, 0, stream>>>(
        Hh, Hl, Wh2, Wl2, c2_b, bn2_g, bn2_b, bn2_m, bn2_v,
        Y0h, Y0l, nullptr, nullptr, (float*)d_out);
}

// Round 5
// 315.057 us; speedup vs baseline: 1.1877x; 1.1034x over previous
//
#include <hip/hip_runtime.h>
#include <hip/hip_bf16.h>

#define BB 16
#define NN 4096
#define SS 1024
#define C1 128
#define C2 256
#define CIN 384
#define CO 128

#define KCH 8            // knn S-chunks
#define SCH (SS / KCH)   // 128 points per chunk

typedef __bf16 bf16x8 __attribute__((ext_vector_type(8)));
typedef float f32x4 __attribute__((ext_vector_type(4)));

// ------- Kernel 1a: partial 3-NN scan over one S-chunk ---------------------
// FROZEN ARITHMETIC (see r12/r2 notes): distance expr + insertion chain
// byte-identical; only the loop range is per-chunk. KCH=8 for occupancy.
__global__ __launch_bounds__(256) void knn_part_kernel(
    const float* __restrict__ xyz1, const float* __restrict__ xyz2,
    float4* __restrict__ pd4, int4* __restrict__ pi4)
{
    __shared__ float4 pts[SCH];   // 2 KB
    const int b = blockIdx.z;
    const int ch = blockIdx.y;
    const float* p2 = xyz2 + ((size_t)b * SS + (size_t)ch * SCH) * 3;
    for (int i = threadIdx.x; i < SCH; i += 256) {
        float x = p2[i * 3 + 0], y = p2[i * 3 + 1], z = p2[i * 3 + 2];
        pts[i] = make_float4(x, y, z, x * x + y * y + z * z);
    }
    __syncthreads();

    const int n = blockIdx.x * 256 + threadIdx.x;
    const float* p1 = xyz1 + ((size_t)b * NN + n) * 3;
    const float x = p1[0], y = p1[1], z = p1[2];
    const float s1 = x * x + y * y + z * z;

    float d0 = 3.4e38f, d1 = 3.4e38f, d2 = 3.4e38f, d3 = 3.4e38f;
    int i0 = 0, i1 = 0, i2 = 0, i3 = 0;
    const int sbase = ch * SCH;
    #pragma unroll 4
    for (int sl = 0; sl < SCH; ++sl) {
        float4 p = pts[sl];
        float d = s1 + p.w - 2.0f * (x * p.x + y * p.y + z * p.z);
        int s = sbase + sl;
        bool lt0 = d < d0, lt1 = d < d1, lt2 = d < d2, lt3 = d < d3;
        float nd3 = lt2 ? d2 : (lt3 ? d : d3); int ni3 = lt2 ? i2 : (lt3 ? s : i3);
        float nd2 = lt1 ? d1 : (lt2 ? d : d2); int ni2 = lt1 ? i1 : (lt2 ? s : i2);
        float nd1 = lt0 ? d0 : (lt1 ? d : d1); int ni1 = lt0 ? i0 : (lt1 ? s : i1);
        d0 = lt0 ? d : d0;                     i0 = lt0 ? s : i0;
        d1 = nd1; i1 = ni1; d2 = nd2; i2 = ni2; d3 = nd3; i3 = ni3;
    }
    size_t o = ((size_t)b * NN + n) * KCH + ch;
    pd4[o] = make_float4(d0, d1, d2, d3);
    pi4[o] = make_int4(i0, i1, i2, i3);
}

// ------- Kernel 1b: merge per-chunk top-4 -> global top-4 + weights --------
// Identical strict-< insertion chain; candidates arrive in (chunk, asc-d)
// order which preserves the sequential scan's (d, s) tie ordering.
__global__ __launch_bounds__(256) void knn_merge_kernel(
    const float4* __restrict__ pd4, const int4* __restrict__ pi4,
    int* __restrict__ idx4, float* __restrict__ w4)
{
    const int n = blockIdx.x * 256 + threadIdx.x;
    const int b = blockIdx.y;
    const size_t o = ((size_t)b * NN + n) * KCH;

    float d0 = 3.4e38f, d1 = 3.4e38f, d2 = 3.4e38f, d3 = 3.4e38f;
    int i0 = 0, i1 = 0, i2 = 0, i3 = 0;
    #pragma unroll
    for (int ch = 0; ch < KCH; ++ch) {
        float4 pd = pd4[o + ch];
        int4 pi = pi4[o + ch];
        float cd[4] = { pd.x, pd.y, pd.z, pd.w };
        int   ci[4] = { pi.x, pi.y, pi.z, pi.w };
        #pragma unroll
        for (int k = 0; k < 4; ++k) {
            float d = cd[k]; int s = ci[k];
            bool lt0 = d < d0, lt1 = d < d1, lt2 = d < d2, lt3 = d < d3;
            float nd3 = lt2 ? d2 : (lt3 ? d : d3); int ni3 = lt2 ? i2 : (lt3 ? s : i3);
            float nd2 = lt1 ? d1 : (lt2 ? d : d2); int ni2 = lt1 ? i1 : (lt2 ? s : i2);
            float nd1 = lt0 ? d0 : (lt1 ? d : d1); int ni1 = lt0 ? i0 : (lt1 ? s : i1);
            d0 = lt0 ? d : d0;                     i0 = lt0 ? s : i0;
            d1 = nd1; i1 = ni1; d2 = nd2; i2 = ni2; d3 = nd3; i3 = ni3;
        }
    }
    float r0 = 1.0f / (d0 + 1e-8f);
    float r1 = 1.0f / (d1 + 1e-8f);
    float r2 = 1.0f / (d2 + 1e-8f);
    float rs = r0 + r1 + r2;
    bool tie = (d2 == d3);
    size_t base = ((size_t)b * NN + n) * 4;
    idx4[base + 0] = i0; idx4[base + 1] = i1;
    idx4[base + 2] = i2; idx4[base + 3] = i3;
    w4[base + 0] = r0 / rs; w4[base + 1] = r1 / rs;
    w4[base + 2] = r2 / rs; w4[base + 3] = tie ? -1.0f : 0.0f;
}

// ---------------- Kernel 2: transpose points2 f32[C2,S] -> f32[S,C2] -------
__global__ __launch_bounds__(256) void p2t_kernel(
    const float* __restrict__ p2, float* __restrict__ p2t)
{
    __shared__ float tile[64][65];
    const int b = blockIdx.z;
    const int s0 = blockIdx.x * 64, c0 = blockIdx.y * 64;
    for (int i = threadIdx.x; i < 64 * 64; i += 256) {
        int s = i & 63, c = i >> 6;
        tile[c][s] = p2[((size_t)b * C2 + c0 + c) * SS + s0 + s];
    }
    __syncthreads();
    for (int i = threadIdx.x; i < 64 * 64; i += 256) {
        int c = i & 63, s = i >> 6;
        p2t[((size_t)b * SS + s0 + s) * C2 + c0 + c] = tile[c][s];
    }
}

// ------- Kernel 2c: split conv weights f32 -> bf16 hi/lo planes (once) -----
__global__ __launch_bounds__(256) void wprep_kernel(
    const float* __restrict__ fw, const float* __restrict__ w1,
    const float* __restrict__ w2,
    __bf16* __restrict__ Whf, __bf16* __restrict__ Wlf,
    __bf16* __restrict__ Wh1, __bf16* __restrict__ Wl1,
    __bf16* __restrict__ Wh2, __bf16* __restrict__ Wl2)
{
    int t = blockIdx.x * 256 + threadIdx.x;
    float v; __bf16 *oh, *ol; int idx;
    if (t < 49152)      { idx = t;         v = fw[idx]; oh = Whf; ol = Wlf; }
    else if (t < 65536) { idx = t - 49152; v = w1[idx]; oh = Wh1; ol = Wl1; }
    else                { idx = t - 65536; v = w2[idx]; oh = Wh2; ol = Wl2; }
    __bf16 h = (__bf16)v;
    oh[idx] = h; ol[idx] = (__bf16)(v - (float)h);
}

// ------- Kernel 2b: tie resolver (unchanged logic from r12) ----------------
__global__ __launch_bounds__(256) void tie_eval_kernel(
    const float* __restrict__ p2t, const float* __restrict__ points1,
    const int* __restrict__ idx4, float* __restrict__ w4,
    const float* __restrict__ fw, const float* __restrict__ fb,
    const float* __restrict__ fg, const float* __restrict__ fbt,
    const float* __restrict__ fm, const float* __restrict__ fv,
    const float* __restrict__ w1m, const float* __restrict__ b1,
    const float* __restrict__ g1, const float* __restrict__ bt1,
    const float* __restrict__ m1, const float* __restrict__ v1,
    const float* __restrict__ w2m, const float* __restrict__ b2,
    const float* __restrict__ g2, const float* __restrict__ bt2,
    const float* __restrict__ m2, const float* __restrict__ v2)
{
    __shared__ float Xs[4][2][CIN];
    __shared__ float XT[4][2][CO];
    __shared__ float Hs[4][2][CO];
    const int wave = threadIdx.x >> 6, lane = threadIdx.x & 63;
    const int n = blockIdx.x * 4 + wave;
    const int b = blockIdx.y;
    const size_t base = ((size_t)b * NN + n) * 4;
    if (w4[base + 3] != -1.0f) return;

    const int i0 = idx4[base + 0], i1 = idx4[base + 1];
    const int i2 = idx4[base + 2], i3 = idx4[base + 3];
    const float w0 = w4[base + 0], w1 = w4[base + 1], w2 = w4[base + 2];
    const float* P = p2t + (size_t)b * SS * C2;

    for (int c = lane; c < C1; c += 64) {
        float v = points1[((size_t)b * C1 + c) * NN + n];
        Xs[wave][0][c] = v; Xs[wave][1][c] = v;
    }
    for (int c = lane; c < C2; c += 64) {
        float f0 = P[(size_t)i0 * C2 + c], f1 = P[(size_t)i1 * C2 + c];
        float f2 = P[(size_t)i2 * C2 + c], f3 = P[(size_t)i3 * C2 + c];
        float bs = w0 * f0 + w1 * f1;
        Xs[wave][0][C1 + c] = bs + w2 * f2;
        Xs[wave][1][C1 + c] = bs + w2 * f3;
    }
    #pragma unroll
    for (int k = 0; k < 2; ++k) {
        int oc = lane + 64 * k;
        float alo = fb[oc], ahi = fb[oc];
        for (int c = 0; c < CIN; ++c) {
            float wv = fw[(size_t)oc * CIN + c];
            alo += wv * Xs[wave][0][c];
            ahi += wv * Xs[wave][1][c];
        }
        float s = fg[oc] * (1.0f / sqrtf(fv[oc] + 1e-5f));
        XT[wave][0][oc] = fmaxf(s * (alo - fm[oc]) + fbt[oc], 0.0f);
        XT[wave][1][oc] = fmaxf(s * (ahi - fm[oc]) + fbt[oc], 0.0f);
    }
    #pragma unroll
    for (int k = 0; k < 2; ++k) {
        int oc = lane + 64 * k;
        float alo = b1[oc], ahi = b1[oc];
        for (int c = 0; c < CO; ++c) {
            float wv = w1m[(size_t)oc * CO + c];
            alo += wv * XT[wave][0][c];
            ahi += wv * XT[wave][1][c];
        }
        float s = g1[oc] * (1.0f / sqrtf(v1[oc] + 1e-5f));
        Hs[wave][0][oc] = fmaxf(s * (alo - m1[oc]) + bt1[oc], 0.0f);
        Hs[wave][1][oc] = fmaxf(s * (ahi - m1[oc]) + bt1[oc], 0.0f);
    }
    float e = 0.0f;
    #pragma unroll
    for (int k = 0; k < 2; ++k) {
        int oc = lane + 64 * k;
        float alo = b2[oc], ahi = b2[oc];
        for (int c = 0; c < CO; ++c) {
            float wv = w2m[(size_t)oc * CO + c];
            alo += wv * Hs[wave][0][c];
            ahi += wv * Hs[wave][1][c];
        }
        float s = g2[oc] * (1.0f / sqrtf(v2[oc] + 1e-5f));
        float olo = fmaxf(s * (alo - m2[oc]) + bt2[oc] + XT[wave][0][oc], 0.0f);
        float ohi = fmaxf(s * (ahi - m2[oc]) + bt2[oc] + XT[wave][1][oc], 0.0f);
        e = fmaxf(e, fabsf(olo - ohi));
    }
    for (int off = 32; off; off >>= 1) e = fmaxf(e, __shfl_xor(e, off));
    if (lane == 0) {
        if (e > 0.085f) { w4[base + 3] = 0.0f; }
        else { w4[base + 2] = 0.5f * w2; w4[base + 3] = 0.5f * w2; }
    }
}

// ------- Kernel 4: FUSED GEMM1 (interp + concat + conv + BN + ReLU) --------
// A-fragments built on the fly, arithmetic expression-identical to the old
// buildx1/buildx2 (same hi/lo split, same interp FMA order) so Y0 is
// bit-identical to the r4 pipeline. XCD-chunked swizzle: 512 blocks = 8 x 64,
// each XCD's chunk covers 2 batches -> gather working set 2 MB, L2-resident.
__global__ __launch_bounds__(256) void gemm1f_kernel(
    const float* __restrict__ points1, const float* __restrict__ p2t,
    const int* __restrict__ idx4, const float* __restrict__ w4,
    const __bf16* __restrict__ Wh, const __bf16* __restrict__ Wl,
    const float* __restrict__ cb,  const float* __restrict__ gg,
    const float* __restrict__ bbta, const float* __restrict__ mm,
    const float* __restrict__ vv,
    __bf16* __restrict__ outh, __bf16* __restrict__ outl)
{
    __shared__ __attribute__((aligned(16))) __bf16 wls_h[128 * 40]; // 10 KB
    __shared__ __attribute__((aligned(16))) __bf16 wls_l[128 * 40]; // 10 KB
    __shared__ float s_s[128], s_t[128];
    const int tid = threadIdx.x;
    if (tid < 128) {
        float s = gg[tid] * (1.0f / sqrtf(vv[tid] + 1e-5f));
        float t = (cb[tid] - mm[tid]) * s + bbta[tid];
        s_s[tid] = s; s_t[tid] = t;
    }
    const int bid = (blockIdx.x & 7) * 64 + (blockIdx.x >> 3);  // bijective
    const int b = bid >> 5;                 // 32 row-blocks per batch
    const int nbase = (bid & 31) * 128;
    const int wave = tid >> 6, lane = tid & 63;
    const int m = lane & 15, q = lane >> 4;

    // per-lane rows: a = nbase+wave*32+m, b-row = a+16
    const size_t pa = (size_t)b * NN + nbase + wave * 32 + m;
    const int4   ia4 = *(const int4*)&idx4[pa * 4];
    const float4 wa4 = *(const float4*)&w4[pa * 4];
    const int4   ib4 = *(const int4*)&idx4[(pa + 16) * 4];
    const float4 wb4 = *(const float4*)&w4[(pa + 16) * 4];
    const float* P = p2t + (size_t)b * SS * C2;

    f32x4 acc[2][8] = {};
    const int wrow = tid >> 1, whf = tid & 1;

    for (int kk = 0; kk < CIN; kk += 32) {
        __syncthreads();
        {   // stage Wh/Wl tile (identical to the r4 staging)
            size_t g = (size_t)wrow * CIN + kk + whf * 16;
            int lo = wrow * 40 + whf * 16;
            *(uint4*)&wls_h[lo]     = *(const uint4*)&Wh[g];
            *(uint4*)&wls_h[lo + 8] = *(const uint4*)&Wh[g + 8];
            *(uint4*)&wls_l[lo]     = *(const uint4*)&Wl[g];
            *(uint4*)&wls_l[lo + 8] = *(const uint4*)&Wl[g + 8];
        }
        __syncthreads();

        bf16x8 ah0, al0, ah1, al1;
        if (kk < C1) {
            // points1 path: same split as buildx1
            const float* p1 = points1 + ((size_t)b * C1 + kk + q * 8) * NN
                            + nbase + wave * 32 + m;
            #pragma unroll
            for (int j = 0; j < 8; ++j) {
                float v = p1[(size_t)j * NN];
                __bf16 h = (__bf16)v;
                ah0[j] = h; al0[j] = (__bf16)(v - (float)h);
            }
            #pragma unroll
            for (int j = 0; j < 8; ++j) {
                float v = p1[(size_t)j * NN + 16];
                __bf16 h = (__bf16)v;
                ah1[j] = h; al1[j] = (__bf16)(v - (float)h);
            }
        } else {
            // interp gather path: same expression order as buildx2
            const int c0 = kk - C1 + q * 8;
            const float* g0 = P + (size_t)ia4.x * C2 + c0;
            const float* g1 = P + (size_t)ia4.y * C2 + c0;
            const float* g2 = P + (size_t)ia4.z * C2 + c0;
            const float* g3 = P + (size_t)ia4.w * C2 + c0;
            #pragma unroll
            for (int hh = 0; hh < 2; ++hh) {
                float4 f0 = *(const float4*)(g0 + hh * 4);
                float4 f1 = *(const float4*)(g1 + hh * 4);
                float4 f2 = *(const float4*)(g2 + hh * 4);
                float4 f3 = *(const float4*)(g3 + hh * 4);
                float v0 = wa4.x * f0.x + wa4.y * f1.x + wa4.z * f2.x + wa4.w * f3.x;
                float v1 = wa4.x * f0.y + wa4.y * f1.y + wa4.z * f2.y + wa4.w * f3.y;
                float v2 = wa4.x * f0.z + wa4.y * f1.z + wa4.z * f2.z + wa4.w * f3.z;
                float v3 = wa4.x * f0.w + wa4.y * f1.w + wa4.z * f2.w + wa4.w * f3.w;
                __bf16 h0 = (__bf16)v0, h1 = (__bf16)v1, h2 = (__bf16)v2, h3 = (__bf16)v3;
                ah0[hh * 4 + 0] = h0; al0[hh * 4 + 0] = (__bf16)(v0 - (float)h0);
                ah0[hh * 4 + 1] = h1; al0[hh * 4 + 1] = (__bf16)(v1 - (float)h1);
                ah0[hh * 4 + 2] = h2; al0[hh * 4 + 2] = (__bf16)(v2 - (float)h2);
                ah0[hh * 4 + 3] = h3; al0[hh * 4 + 3] = (__bf16)(v3 - (float)h3);
            }
            const float* e0 = P + (size_t)ib4.x * C2 + c0;
            const float* e1 = P + (size_t)ib4.y * C2 + c0;
            const float* e2 = P + (size_t)ib4.z * C2 + c0;
            const float* e3 = P + (size_t)ib4.w * C2 + c0;
            #pragma unroll
            for (int hh = 0; hh < 2; ++hh) {
                float4 f0 = *(const float4*)(e0 + hh * 4);
                float4 f1 = *(const float4*)(e1 + hh * 4);
                float4 f2 = *(const float4*)(e2 + hh * 4);
                float4 f3 = *(const float4*)(e3 + hh * 4);
                float v0 = wb4.x * f0.x + wb4.y * f1.x + wb4.z * f2.x + wb4.w * f3.x;
                float v1 = wb4.x * f0.y + wb4.y * f1.y + wb4.z * f2.y + wb4.w * f3.y;
                float v2 = wb4.x * f0.z + wb4.y * f1.z + wb4.z * f2.z + wb4.w * f3.z;
                float v3 = wb4.x * f0.w + wb4.y * f1.w + wb4.z * f2.w + wb4.w * f3.w;
                __bf16 h0 = (__bf16)v0, h1 = (__bf16)v1, h2 = (__bf16)v2, h3 = (__bf16)v3;
                ah1[hh * 4 + 0] = h0; al1[hh * 4 + 0] = (__bf16)(v0 - (float)h0);
                ah1[hh * 4 + 1] = h1; al1[hh * 4 + 1] = (__bf16)(v1 - (float)h1);
                ah1[hh * 4 + 2] = h2; al1[hh * 4 + 2] = (__bf16)(v2 - (float)h2);
                ah1[hh * 4 + 3] = h3; al1[hh * 4 + 3] = (__bf16)(v3 - (float)h3);
            }
        }

        #pragma unroll
        for (int ot = 0; ot < 8; ++ot) {
            bf16x8 bh = *(const bf16x8*)&wls_h[(ot * 16 + m) * 40 + q * 8];
            bf16x8 bl = *(const bf16x8*)&wls_l[(ot * 16 + m) * 40 + q * 8];
            acc[0][ot] = __builtin_amdgcn_mfma_f32_16x16x32_bf16(ah0, bh, acc[0][ot], 0, 0, 0);
            acc[0][ot] = __builtin_amdgcn_mfma_f32_16x16x32_bf16(al0, bh, acc[0][ot], 0, 0, 0);
            acc[0][ot] = __builtin_amdgcn_mfma_f32_16x16x32_bf16(ah0, bl, acc[0][ot], 0, 0, 0);
            acc[1][ot] = __builtin_amdgcn_mfma_f32_16x16x32_bf16(ah1, bh, acc[1][ot], 0, 0, 0);
            acc[1][ot] = __builtin_amdgcn_mfma_f32_16x16x32_bf16(al1, bh, acc[1][ot], 0, 0, 0);
            acc[1][ot] = __builtin_amdgcn_mfma_f32_16x16x32_bf16(ah1, bl, acc[1][ot], 0, 0, 0);
        }
    }

    const size_t r0 = (size_t)bid * 128 + wave * 32;
    #pragma unroll
    for (int rt = 0; rt < 2; ++rt) {
        #pragma unroll
        for (int ot = 0; ot < 8; ++ot) {
            int col = ot * 16 + m;
            float sc = s_s[col], sh = s_t[col];
            #pragma unroll
            for (int r = 0; r < 4; ++r) {
                size_t row = r0 + rt * 16 + q * 4 + r;
                float val = fmaxf(acc[rt][ot][r] * sc + sh, 0.0f);
                __bf16 h = (__bf16)val;
                outh[row * 128 + col] = h;
                outl[row * 128 + col] = (__bf16)(val - (float)h);
            }
        }
    }
}

// ------- Kernels 5-6: split-bf16 MFMA GEMM v2 (unchanged) ------------------
template<int K, int MODE>
__global__ __launch_bounds__(256) void gemm_bn_kernel(
    const __bf16* __restrict__ Ah, const __bf16* __restrict__ Al,
    const __bf16* __restrict__ Wh, const __bf16* __restrict__ Wl,
    const float* __restrict__ cb,  const float* __restrict__ gg,
    const float* __restrict__ bbta, const float* __restrict__ mm,
    const float* __restrict__ vv,
    const __bf16* __restrict__ skiph, const __bf16* __restrict__ skipl,
    __bf16* __restrict__ outh, __bf16* __restrict__ outl,
    float* __restrict__ outf)
{
    __shared__ __attribute__((aligned(16))) __bf16 wls_h[128 * 40]; // 10 KB
    __shared__ __attribute__((aligned(16))) __bf16 wls_l[128 * 40]; // 10 KB
    __shared__ float s_s[128], s_t[128];
    __shared__ float tile[32][132];   // MODE1 transpose staging
    const int tid = threadIdx.x;
    if (tid < 128) {
        float s = gg[tid] * (1.0f / sqrtf(vv[tid] + 1e-5f));
        float t = (cb[tid] - mm[tid]) * s + bbta[tid];
        s_s[tid] = s; s_t[tid] = t;
    }
    const int wave = tid >> 6, lane = tid & 63;
    const int m = lane & 15, q = lane >> 4;
    const size_t r0 = (size_t)blockIdx.x * 128 + wave * 32;

    f32x4 acc[2][8] = {};
    const __bf16* pAh = Ah + (r0 + m) * (size_t)K + q * 8;
    const __bf16* pAl = Al + (r0 + m) * (size_t)K + q * 8;

    const int wrow = tid >> 1, whf = tid & 1;
    for (int kk = 0; kk < K; kk += 32) {
        __syncthreads();
        {   // stage Wh/Wl tile (each thread: 16 elems per plane)
            size_t g = (size_t)wrow * K + kk + whf * 16;
            int lo = wrow * 40 + whf * 16;
            *(uint4*)&wls_h[lo]     = *(const uint4*)&Wh[g];
            *(uint4*)&wls_h[lo + 8] = *(const uint4*)&Wh[g + 8];
            *(uint4*)&wls_l[lo]     = *(const uint4*)&Wl[g];
            *(uint4*)&wls_l[lo + 8] = *(const uint4*)&Wl[g + 8];
        }
        __syncthreads();
        bf16x8 ah0 = *(const bf16x8*)(pAh + kk);
        bf16x8 al0 = *(const bf16x8*)(pAl + kk);
        bf16x8 ah1 = *(const bf16x8*)(pAh + 16 * (size_t)K + kk);
        bf16x8 al1 = *(const bf16x8*)(pAl + 16 * (size_t)K + kk);
        #pragma unroll
        for (int ot = 0; ot < 8; ++ot) {
            bf16x8 bh = *(const bf16x8*)&wls_h[(ot * 16 + m) * 40 + q * 8];
            bf16x8 bl = *(const bf16x8*)&wls_l[(ot * 16 + m) * 40 + q * 8];
            acc[0][ot] = __builtin_amdgcn_mfma_f32_16x16x32_bf16(ah0, bh, acc[0][ot], 0, 0, 0);
            acc[0][ot] = __builtin_amdgcn_mfma_f32_16x16x32_bf16(al0, bh, acc[0][ot], 0, 0, 0);
            acc[0][ot] = __builtin_amdgcn_mfma_f32_16x16x32_bf16(ah0, bl, acc[0][ot], 0, 0, 0);
            acc[1][ot] = __builtin_amdgcn_mfma_f32_16x16x32_bf16(ah1, bh, acc[1][ot], 0, 0, 0);
            acc[1][ot] = __builtin_amdgcn_mfma_f32_16x16x32_bf16(al1, bh, acc[1][ot], 0, 0, 0);
            acc[1][ot] = __builtin_amdgcn_mfma_f32_16x16x32_bf16(ah1, bl, acc[1][ot], 0, 0, 0);
        }
    }

    if (MODE == 0) {
        #pragma unroll
        for (int rt = 0; rt < 2; ++rt) {
            #pragma unroll
            for (int ot = 0; ot < 8; ++ot) {
                int col = ot * 16 + m;
                float sc = s_s[col], sh = s_t[col];
                #pragma unroll
                for (int r = 0; r < 4; ++r) {
                    size_t row = r0 + rt * 16 + q * 4 + r;
                    float val = fmaxf(acc[rt][ot][r] * sc + sh, 0.0f);
                    __bf16 h = (__bf16)val;
                    outh[row * 128 + col] = h;
                    outl[row * 128 + col] = (__bf16)(val - (float)h);
                }
            }
        }
    } else {
        const int bidx = (int)(((size_t)blockIdx.x * 128) >> 12);
        const int nbase = (int)(((size_t)blockIdx.x * 128) & 4095);
        for (int cc = 0; cc < 4; ++cc) {
            __syncthreads();
            #pragma unroll
            for (int oo = 0; oo < 2; ++oo) {
                int ot = cc * 2 + oo;
                int col = ot * 16 + m;
                float sc = s_s[col], sh = s_t[col];
                #pragma unroll
                for (int rt = 0; rt < 2; ++rt) {
                    #pragma unroll
                    for (int r = 0; r < 4; ++r) {
                        int lrow = wave * 32 + rt * 16 + q * 4 + r;
                        size_t row = (size_t)blockIdx.x * 128 + lrow;
                        float val = acc[rt][ot][r] * sc + sh;
                        val += (float)skiph[row * 128 + col] + (float)skipl[row * 128 + col];
                        val = fmaxf(val, 0.0f);
                        tile[oo * 16 + m][lrow] = val;
                    }
                }
            }
            __syncthreads();
            for (int c2 = tid >> 7; c2 < 32; c2 += 2) {
                int nn_ = tid & 127;
                outf[((size_t)bidx * 128 + cc * 32 + c2) * NN + nbase + nn_] = tile[c2][nn_];
            }
        }
    }
}

extern "C" void kernel_launch(void* const* d_in, const int* in_sizes, int n_in,
                              void* d_out, int out_size, void* d_ws, size_t ws_size,
                              hipStream_t stream) {
    const float* xyz1    = (const float*)d_in[0];
    const float* xyz2    = (const float*)d_in[1];
    const float* points1 = (const float*)d_in[2];
    const float* points2 = (const float*)d_in[3];
    const float* fuse_w  = (const float*)d_in[4];
    const float* fuse_b  = (const float*)d_in[5];
    const float* fuse_g  = (const float*)d_in[6];
    const float* fuse_bt = (const float*)d_in[7];
    const float* fuse_m  = (const float*)d_in[8];
    const float* fuse_v  = (const float*)d_in[9];
    const float* c1_w    = (const float*)d_in[10];
    const float* c1_b    = (const float*)d_in[11];
    const float* bn1_g   = (const float*)d_in[12];
    const float* bn1_b   = (const float*)d_in[13];
    const float* bn1_m   = (const float*)d_in[14];
    const float* bn1_v   = (const float*)d_in[15];
    const float* c2_w    = (const float*)d_in[16];
    const float* c2_b    = (const float*)d_in[17];
    const float* bn2_g   = (const float*)d_in[18];
    const float* bn2_b   = (const float*)d_in[19];
    const float* bn2_m   = (const float*)d_in[20];
    const float* bn2_v   = (const float*)d_in[21];

    char* ws = (char*)d_ws;
    int*    idx4 = (int*)(ws);                      // 1 MB
    float*  w4   = (float*)(ws + 1048576);          // 1 MB
    float*  p2t  = (float*)(ws + 2097152);          // 16.78 MB
    __bf16* Y0h  = (__bf16*)(ws + 119537664);       // 16 MB
    __bf16* Y0l  = (__bf16*)(ws + 136314880);       // 16 MB
    __bf16* Hh   = (__bf16*)(ws + 153092096);       // 16 MB
    __bf16* Hl   = (__bf16*)(ws + 169869312);       // 16 MB
    __bf16* Whf  = (__bf16*)(ws + 186646528);       // 96 KB
    __bf16* Wlf  = (__bf16*)(ws + 186744832);       // 96 KB
    __bf16* Wh1  = (__bf16*)(ws + 186843136);       // 32 KB
    __bf16* Wl1  = (__bf16*)(ws + 186875904);       // 32 KB
    __bf16* Wh2  = (__bf16*)(ws + 186908672);       // 32 KB
    __bf16* Wl2  = (__bf16*)(ws + 186941440);       // 32 KB

    // knn partials live in the (now unused) former-X region.
    float4* pd4 = (float4*)(ws + 18874368);                 // 8 MB
    int4*   pi4 = (int4*)(ws + 18874368 + 8388608);         // 8 MB

    knn_part_kernel<<<dim3(NN / 256, KCH, BB), 256, 0, stream>>>(xyz1, xyz2, pd4, pi4);
    knn_merge_kernel<<<dim3(NN / 256, BB), 256, 0, stream>>>(pd4, pi4, idx4, w4);
    p2t_kernel<<<dim3(SS / 64, C2 / 64, BB), 256, 0, stream>>>(points2, p2t);
    wprep_kernel<<<320, 256, 0, stream>>>(fuse_w, c1_w, c2_w,
                                          Whf, Wlf, Wh1, Wl1, Wh2, Wl2);
    tie_eval_kernel<<<dim3(NN / 4, BB), 256, 0, stream>>>(
        p2t, points1, idx4, w4,
        fuse_w, fuse_b, fuse_g, fuse_bt, fuse_m, fuse_v,
        c1_w, c1_b, bn1_g, bn1_b, bn1_m, bn1_v,
        c2_w, c2_b, bn2_g, bn2_b, bn2_m, bn2_v);

    const int gblocks = (BB * NN) / 128;   // 512
    gemm1f_kernel<<<gblocks, 256, 0, stream>>>(
        points1, p2t, idx4, w4, Whf, Wlf,
        fuse_b, fuse_g, fuse_bt, fuse_m, fuse_v, Y0h, Y0l);
    gemm_bn_kernel<CO, 0><<<gblocks, 256, 0, stream>>>(
        Y0h, Y0l, Wh1, Wl1, c1_b, bn1_g, bn1_b, bn1_m, bn1_v,
        nullptr, nullptr, Hh, Hl, nullptr);
    gemm_bn_kernel<CO, 1><<<gblocks, 256, 0, stream>>>(
        Hh, Hl, Wh2, Wl2, c2_b, bn2_g, bn2_b, bn2_m, bn2_v,
        Y0h, Y0l, nullptr, nullptr, (float*)d_out);
}